// Round 6
// baseline (308.548 us; speedup 1.0000x reference)
//
#include <hip/hip_runtime.h>
#include <stdint.h>

typedef unsigned short bfu;
typedef __attribute__((ext_vector_type(8))) short bf16x8;   // MFMA A/B frag
typedef __attribute__((ext_vector_type(4))) float f32x4;    // MFMA C/D frag

__device__ __forceinline__ bfu f2b(float f) {
  unsigned int i = __builtin_bit_cast(unsigned int, f);
  i += 0x7FFFu + ((i >> 16) & 1u);  // round-to-nearest-even
  return (bfu)(i >> 16);
}
__device__ __forceinline__ float b2f(bfu b) {
  return __builtin_bit_cast(float, ((unsigned int)b) << 16);
}

// async global->LDS, 16B per lane. LDS dest must be wave-uniform base + lane*16.
__device__ __forceinline__ void stage16(const bfu* g, bfu* l) {
  __builtin_amdgcn_global_load_lds(
      (const __attribute__((address_space(1))) void*)g,
      (__attribute__((address_space(3))) void*)l, 16, 0, 0);
}

// ---------------------------------------------------------------------------
// C[M,N] = A[M,K] @ B[N,K]^T. 64x128 tile, BK=64.
// Prefetch double-buffered, T2 XOR-swizzled LDS. 4 waves 2x2 (acc[2][4]).
// MODE 1: store bf16 via LDS repack. MODE 3: store f32 (split-K partials via
// blockIdx.z when zIsK: k0 = z*Klen, cOff = z*sC).
template <int MODE>
__global__ __launch_bounds__(256) void gemm64p(
    const bfu* __restrict__ A, const bfu* __restrict__ B, void* __restrict__ Cv,
    int lda, int ldb, int ldc,
    long long sA, long long sB, long long sC,
    int Klen, int zIsK) {
  __shared__ __align__(16) bfu S[24576];
  const int tid = threadIdx.x;
  const int lane = tid & 63;
  const int wid = tid >> 6;
  const int l15 = lane & 15, l4 = lane >> 4;
  const int wm = wid >> 1, wn = wid & 1;

  int k0 = 0;
  long long cOff = 0;
  if (zIsK) {
    k0 = blockIdx.z * Klen;
    cOff = (long long)blockIdx.z * sC;
  } else {
    A += (long long)blockIdx.z * sA;
    B += (long long)blockIdx.z * sB;
    cOff = (long long)blockIdx.z * sC;
  }
  const int m0 = blockIdx.y * 64;
  const int n0 = blockIdx.x * 128;
  const bfu* Ag = A + (long long)m0 * lda + k0;
  const bfu* Bg = B + (long long)n0 * ldb + k0;

  f32x4 acc[2][4];
  const f32x4 zero = {0.f, 0.f, 0.f, 0.f};
#pragma unroll
  for (int r = 0; r < 2; ++r)
#pragma unroll
    for (int c = 0; c < 4; ++c) acc[r][c] = zero;

  const int lrow = lane >> 3;
  const int ldst = (lane & 7) * 8;
  const int lsrc = ldst ^ (lrow * 8);
  const int ksw = (l15 & 7) * 8;

  const int nIter = Klen >> 6;

  auto STAGE = [&](int kt, bfu* buf) {
    const bfu* Ak = Ag + kt * 64;
    const bfu* Bk = Bg + kt * 64;
#pragma unroll
    for (int j = 0; j < 2; ++j) {
      const int row = (wid * 2 + j) * 8 + lrow;
      stage16(Ak + (long long)row * lda + lsrc, buf + row * 64 + ldst);
    }
#pragma unroll
    for (int j = 0; j < 4; ++j) {
      const int row = (wid * 4 + j) * 8 + lrow;
      stage16(Bk + (long long)row * ldb + lsrc, buf + 4096 + row * 64 + ldst);
    }
  };

  STAGE(0, S);
  asm volatile("s_waitcnt vmcnt(0)" ::: "memory");
  __builtin_amdgcn_s_barrier();

  int cur = 0;
  for (int kt = 0; kt < nIter; ++kt) {
    bfu* bufc = S + (cur ? 12288 : 0);
    bfu* bufn = S + (cur ? 0 : 12288);
    if (kt + 1 < nIter) STAGE(kt + 1, bufn);
#pragma unroll
    for (int kk = 0; kk < 2; ++kk) {
      const int ko = (kk * 32 + l4 * 8) ^ ksw;
      bf16x8 af[2], bfr[4];
#pragma unroll
      for (int r = 0; r < 2; ++r)
        af[r] = *(const bf16x8*)(bufc + (wm * 32 + r * 16 + l15) * 64 + ko);
#pragma unroll
      for (int c = 0; c < 4; ++c)
        bfr[c] = *(const bf16x8*)(bufc + 4096 + (wn * 64 + c * 16 + l15) * 64 + ko);
#pragma unroll
      for (int r = 0; r < 2; ++r)
#pragma unroll
        for (int c = 0; c < 4; ++c)
          acc[r][c] = __builtin_amdgcn_mfma_f32_16x16x32_bf16(af[r], bfr[c], acc[r][c], 0, 0, 0);
    }
    asm volatile("s_waitcnt vmcnt(0)" ::: "memory");
    __builtin_amdgcn_s_barrier();
    cur ^= 1;
  }

  if (MODE == 3) {
    float* Cf = (float*)Cv;
#pragma unroll
    for (int r = 0; r < 2; ++r) {
#pragma unroll
      for (int c = 0; c < 4; ++c) {
        const int gr = m0 + wm * 32 + r * 16 + (l4 << 2);
        const int gc = n0 + wn * 64 + c * 16 + l15;
#pragma unroll
        for (int v = 0; v < 4; ++v)
          Cf[cOff + (long long)(gr + v) * ldc + gc] = acc[r][c][v];
      }
    }
  } else {
    // bf16 epilogue: repack 64x128 C tile via LDS (XOR-swizzled), 16B stores.
#pragma unroll
    for (int r = 0; r < 2; ++r) {
#pragma unroll
      for (int c = 0; c < 4; ++c) {
        const int col = wn * 64 + c * 16 + l15;
#pragma unroll
        for (int v = 0; v < 4; ++v) {
          const int row = wm * 32 + r * 16 + (l4 << 2) + v;
          S[row * 128 + (col ^ (((row >> 2) & 3) << 4))] = f2b(acc[r][c][v]);
        }
      }
    }
    __syncthreads();
    bfu* Cb = (bfu*)Cv;
#pragma unroll
    for (int i = 0; i < 4; ++i) {
      const int j = i * 256 + tid;
      const int row = j >> 4;
      const int colbase = (j & 15) * 8;
      const int sc = colbase ^ (((row >> 2) & 3) << 4);
      uint4 val = *(const uint4*)(S + row * 128 + sc);
      *(uint4*)(Cb + cOff + (long long)(m0 + row) * ldc + n0 + colbase) = val;
    }
  }
}

// ---------------------------------------------------------------------------
// Fused logits+exp GEMM (round-4 gemm128p structure, proven 50.5us, 2 blk/CU):
//   Ecat[s][h*512+a] = bf16(exp((X[s,:]@M_h[a,:]^T + cb[h,a]) / sqrt(512)))
// UNNORMALIZED (no max-sub: logits ~N(0,1.2), |x|<~6 -> exp in [2e-3, 4e2]).
// Row-sum partials (from the bf16-ROUNDED values, consistent with stored
// numerator) go to ddp[s*32 + h*4 + bx]; normalization happens in gemm_fin.
__global__ __launch_bounds__(256) void gemm_sme(
    const bfu* __restrict__ Xb, const bfu* __restrict__ Mb,
    bfu* __restrict__ Ecat, const float* __restrict__ cb,
    float* __restrict__ ddp) {
  __shared__ __align__(16) bfu S[32768];  // 2 x (At 128x64 + Bt 128x64) = 64KB
  const int tid = threadIdx.x;
  const int lane = tid & 63;
  const int wid = tid >> 6;
  const int l15 = lane & 15, l4 = lane >> 4;
  const int wm = wid >> 1, wn = wid & 1;

  // XCD swizzle: nwg=2048, chunk=256; y-major decode.
  const int bid = blockIdx.x;
  const int swz = ((bid & 7) << 8) + (bid >> 3);
  const int by = swz >> 5;        // m-panel 0..63
  const int h  = (swz >> 2) & 7;  // head
  const int bx = swz & 3;         // n-block

  const int m0 = by * 128;
  const int n0l = bx * 128;       // col-block within head
  const bfu* Ag = Xb + (long long)m0 * 512;
  const bfu* Bg = Mb + (long long)h * 262144 + (long long)n0l * 512;

  f32x4 acc[4][4];
  const f32x4 zero = {0.f, 0.f, 0.f, 0.f};
#pragma unroll
  for (int r = 0; r < 4; ++r)
#pragma unroll
    for (int c = 0; c < 4; ++c) acc[r][c] = zero;

  const int lrow = lane >> 3;
  const int ldst = (lane & 7) * 8;
  const int lsrc = ldst ^ (lrow * 8);
  const int ksw = (l15 & 7) * 8;

  auto STAGE = [&](int kt, bfu* buf) {
    const bfu* Ak = Ag + kt * 64;
    const bfu* Bk = Bg + kt * 64;
#pragma unroll
    for (int j = 0; j < 4; ++j) {
      const int row = (wid * 4 + j) * 8 + lrow;
      stage16(Ak + (long long)row * 512 + lsrc, buf + row * 64 + ldst);
    }
#pragma unroll
    for (int j = 0; j < 4; ++j) {
      const int row = (wid * 4 + j) * 8 + lrow;
      stage16(Bk + (long long)row * 512 + lsrc, buf + 8192 + row * 64 + ldst);
    }
  };

  STAGE(0, S);
  asm volatile("s_waitcnt vmcnt(0)" ::: "memory");
  __builtin_amdgcn_s_barrier();

  for (int kt = 0; kt < 8; ++kt) {   // K = 512
    bfu* bufc = S + ((kt & 1) ? 16384 : 0);
    bfu* bufn = S + ((kt & 1) ? 0 : 16384);
    if (kt + 1 < 8) STAGE(kt + 1, bufn);
#pragma unroll
    for (int kk = 0; kk < 2; ++kk) {
      const int ko = (kk * 32 + l4 * 8) ^ ksw;
      bf16x8 af[4], bfr[4];
#pragma unroll
      for (int r = 0; r < 4; ++r)
        af[r] = *(const bf16x8*)(bufc + (wm * 64 + r * 16 + l15) * 64 + ko);
#pragma unroll
      for (int c = 0; c < 4; ++c)
        bfr[c] = *(const bf16x8*)(bufc + 8192 + (wn * 64 + c * 16 + l15) * 64 + ko);
#pragma unroll
      for (int r = 0; r < 4; ++r)
#pragma unroll
        for (int c = 0; c < 4; ++c)
          acc[r][c] = __builtin_amdgcn_mfma_f32_16x16x32_bf16(af[r], bfr[c], acc[r][c], 0, 0, 0);
    }
    asm volatile("s_waitcnt vmcnt(0)" ::: "memory");
    __builtin_amdgcn_s_barrier();
  }

  // ---- exp epilogue ----
  const float scale = 0.044194173824159216f;  // 1/sqrt(512)
  float ch[4];
#pragma unroll
  for (int c = 0; c < 4; ++c)
    ch[c] = cb[h * 512 + n0l + wn * 64 + c * 16 + l15];
  // exp, round to bf16 (acc keeps the ROUNDED value so row sums match the
  // stored numerator exactly)
#pragma unroll
  for (int r = 0; r < 4; ++r)
#pragma unroll
    for (int c = 0; c < 4; ++c)
#pragma unroll
      for (int v = 0; v < 4; ++v)
        acc[r][c][v] = b2f(f2b(__expf((acc[r][c][v] + ch[c]) * scale)));

  // row-sum partials over this tile's 128 cols
  float rs[4][4];
#pragma unroll
  for (int r = 0; r < 4; ++r)
#pragma unroll
    for (int v = 0; v < 4; ++v)
      rs[r][v] = acc[r][0][v] + acc[r][1][v] + acc[r][2][v] + acc[r][3][v];
#pragma unroll
  for (int off = 1; off < 16; off <<= 1)
#pragma unroll
    for (int r = 0; r < 4; ++r)
#pragma unroll
      for (int v = 0; v < 4; ++v)
        rs[r][v] += __shfl_xor(rs[r][v], off, 64);
  float* red = (float*)(S + 16384);   // byte 32768, disjoint from repack area
  if (l15 == 0) {
#pragma unroll
    for (int r = 0; r < 4; ++r)
#pragma unroll
      for (int v = 0; v < 4; ++v)
        red[wn * 128 + wm * 64 + r * 16 + (l4 << 2) + v] = rs[r][v];
  }
  __syncthreads();
  if (tid < 128)
    ddp[(long long)(m0 + tid) * 32 + h * 4 + bx] = red[tid] + red[128 + tid];

  // repack 128x128 bf16 tile (XOR-swizzled) + 16B stores
#pragma unroll
  for (int r = 0; r < 4; ++r)
#pragma unroll
    for (int c = 0; c < 4; ++c) {
      const int col = wn * 64 + c * 16 + l15;
#pragma unroll
      for (int v = 0; v < 4; ++v) {
        const int row = wm * 64 + r * 16 + (l4 << 2) + v;
        S[row * 128 + (col ^ (((row >> 2) & 3) << 4))] = f2b(acc[r][c][v]);
      }
    }
  __syncthreads();
#pragma unroll
  for (int i = 0; i < 8; ++i) {
    const int j = i * 256 + tid;
    const int row = j >> 4;            // 0..127
    const int colbase = (j & 15) * 8;  // 0..120
    const int sc = colbase ^ (((row >> 2) & 3) << 4);
    uint4 val = *(const uint4*)(S + row * 128 + sc);
    *(uint4*)(Ecat + (long long)(m0 + row) * 4096 + h * 512 + n0l + colbase) = val;
  }
}

// invD2[h*8192 + s] = 1 / sum_bx ddp[s*32 + h*4 + bx]
__global__ __launch_bounds__(256) void inv_k(const float* __restrict__ ddp,
                                             float* __restrict__ invD2) {
  const int i = blockIdx.x * 256 + threadIdx.x;  // s*8+h, 65536 total
  f32x4 p = *(const f32x4*)(ddp + (long long)i * 4);
  const int s = i >> 3, h = i & 7;
  invD2[h * 8192 + s] = 1.0f / (p[0] + p[1] + p[2] + p[3]);
}

// ---------------------------------------------------------------------------
// Final GEMM with per-head normalization:
//   out[s][o] = bias[o] + sum_h (1/D[h][s]) * sum_{a} expE[s][h*512+a]*Ncat[o][h*512+a]
// 64x128 tile, 512 blocks (2/CU), PIPE=3 counted vmcnt, XCD swizzle.
// invD2 preloaded to 16 f32x4 BEFORE staging (drained, so vmcnt counts stay
// clean); consumed via static register rotation (no runtime array indexing).
__global__ __launch_bounds__(256) void gemm_fin(
    const bfu* __restrict__ A, const bfu* __restrict__ B, float* __restrict__ C,
    const float* __restrict__ bias, const float* __restrict__ invD2) {
  __shared__ __align__(16) bfu S[36864];  // 3 x 24KB
  const int tid = threadIdx.x;
  const int lane = tid & 63;
  const int wid = tid >> 6;
  const int l15 = lane & 15, l4 = lane >> 4;
  const int wm = wid >> 1, wn = wid & 1;

  const int bid = blockIdx.x;
  const int swz = ((bid & 7) << 6) + (bid >> 3);
  const int m0 = (swz >> 2) * 64;
  const int n0 = (swz & 3) * 128;
  const bfu* Ag = A + (long long)m0 * 4096;
  const bfu* Bg = B + (long long)n0 * 4096;

  // preload inverse denominators: rows m0+wm*32+{0,16}+l4*4+v, per head
  f32x4 inv0[8], inv1[8];
#pragma unroll
  for (int h = 0; h < 8; ++h) {
    const float* p = invD2 + h * 8192 + m0 + wm * 32 + (l4 << 2);
    inv0[h] = *(const f32x4*)p;
    inv1[h] = *(const f32x4*)(p + 16);
  }

  f32x4 macc[2][4], acc[2][4];
  const f32x4 zero = {0.f, 0.f, 0.f, 0.f};
#pragma unroll
  for (int r = 0; r < 2; ++r)
#pragma unroll
    for (int c = 0; c < 4; ++c) { macc[r][c] = zero; acc[r][c] = zero; }

  const int lrow = lane >> 3;
  const int ldst = (lane & 7) * 8;
  const int lsrc = ldst ^ (lrow * 8);
  const int ksw = (l15 & 7) * 8;

  auto STAGE = [&](int kt, bfu* buf) {  // 6 gload_lds per lane
    const bfu* Ak = Ag + kt * 64;
    const bfu* Bk = Bg + kt * 64;
#pragma unroll
    for (int j = 0; j < 2; ++j) {
      const int row = (wid * 2 + j) * 8 + lrow;
      stage16(Ak + (long long)row * 4096 + lsrc, buf + row * 64 + ldst);
    }
#pragma unroll
    for (int j = 0; j < 4; ++j) {
      const int row = (wid * 4 + j) * 8 + lrow;
      stage16(Bk + (long long)row * 4096 + lsrc, buf + 4096 + row * 64 + ldst);
    }
  };

  // drain preloads so staged-load counting below is exact
  asm volatile("s_waitcnt vmcnt(0)" ::: "memory");

  STAGE(0, S);
  STAGE(1, S + 12288);

  for (int kt = 0; kt < 64; ++kt) {   // K = 4096
    if (kt > 0) __builtin_amdgcn_s_barrier();
    if (kt + 2 < 64) STAGE(kt + 2, S + 12288 * ((kt + 2) % 3));
    const int rem = 63 - kt;
    if (rem >= 2)
      asm volatile("s_waitcnt vmcnt(12)" ::: "memory");
    else if (rem == 1)
      asm volatile("s_waitcnt vmcnt(6)" ::: "memory");
    else
      asm volatile("s_waitcnt vmcnt(0)" ::: "memory");
    __builtin_amdgcn_s_barrier();

    const bfu* bufc = S + 12288 * (kt % 3);
#pragma unroll
    for (int kk = 0; kk < 2; ++kk) {
      const int ko = (kk * 32 + l4 * 8) ^ ksw;
      bf16x8 af[2], bfr[4];
#pragma unroll
      for (int r = 0; r < 2; ++r)
        af[r] = *(const bf16x8*)(bufc + (wm * 32 + r * 16 + l15) * 64 + ko);
#pragma unroll
      for (int c = 0; c < 4; ++c)
        bfr[c] = *(const bf16x8*)(bufc + 4096 + (wn * 64 + c * 16 + l15) * 64 + ko);
#pragma unroll
      for (int r = 0; r < 2; ++r)
#pragma unroll
        for (int c = 0; c < 4; ++c)
          acc[r][c] = __builtin_amdgcn_mfma_f32_16x16x32_bf16(af[r], bfr[c], acc[r][c], 0, 0, 0);
    }

    if ((kt & 7) == 7) {  // head boundary: fold seg into master with 1/D
#pragma unroll
      for (int r = 0; r < 2; ++r) {
        const f32x4 iv = r ? inv1[0] : inv0[0];
#pragma unroll
        for (int c = 0; c < 4; ++c) {
#pragma unroll
          for (int v = 0; v < 4; ++v) macc[r][c][v] += acc[r][c][v] * iv[v];
          acc[r][c] = zero;
        }
      }
#pragma unroll
      for (int q = 0; q < 7; ++q) { inv0[q] = inv0[q + 1]; inv1[q] = inv1[q + 1]; }
    }
  }

  // f32 + bias store
#pragma unroll
  for (int r = 0; r < 2; ++r) {
#pragma unroll
    for (int c = 0; c < 4; ++c) {
      const int gr = m0 + wm * 32 + r * 16 + (l4 << 2);
      const int gc = n0 + wn * 64 + c * 16 + l15;
      const float bval = bias[gc];
#pragma unroll
      for (int v = 0; v < 4; ++v)
        C[(long long)(gr + v) * 512 + gc] = macc[r][c][v] + bval;
    }
  }
}

// ---------------- helpers ----------------
__global__ void convT_x(const float* __restrict__ in, bfu* __restrict__ outN,
                        bfu* __restrict__ outT, int R, int C) {
  __shared__ bfu t[32][33];
  const int c0 = blockIdx.x * 32, r0 = blockIdx.y * 32;
  const int tx = threadIdx.x, ty = threadIdx.y;
  for (int i = ty; i < 32; i += 8) {
    bfu b = f2b(in[(long long)(r0 + i) * C + (c0 + tx)]);
    outN[(long long)(r0 + i) * C + (c0 + tx)] = b;
    t[i][tx] = b;
  }
  __syncthreads();
  for (int i = ty; i < 32; i += 8)
    outT[(long long)(c0 + i) * R + (r0 + tx)] = t[tx][i];
}

__global__ void transpose_k(const float* __restrict__ in, bfu* __restrict__ out,
                            int R, int C) {
  __shared__ bfu t[32][33];
  const long long boff = (long long)blockIdx.z * R * C;
  const int c0 = blockIdx.x * 32, r0 = blockIdx.y * 32;
  const int tx = threadIdx.x, ty = threadIdx.y;
  for (int i = ty; i < 32; i += 8)
    t[i][tx] = f2b(in[boff + (long long)(r0 + i) * C + (c0 + tx)]);
  __syncthreads();
  for (int i = ty; i < 32; i += 8)
    out[boff + (long long)(c0 + i) * R + (r0 + tx)] = t[tx][i];
}

__global__ __launch_bounds__(256) void conv_mat(const float* __restrict__ src,
                                                bfu* __restrict__ dst, int count4) {
  int i = blockIdx.x * 256 + threadIdx.x;
  if (i < count4) {
    float4 f = ((const float4*)src)[i];
    ushort4 o;
    o.x = f2b(f.x); o.y = f2b(f.y); o.z = f2b(f.z); o.w = f2b(f.w);
    ((ushort4*)dst)[i] = o;
  }
}

__global__ __launch_bounds__(256) void zero_out_k(float* __restrict__ p, int n) {
  int i = blockIdx.x * 256 + threadIdx.x;
  if (i < n) p[i] = 0.f;
}

// K32[i] = sum_z Kp[z][i]; V32 likewise (replaces split-K atomics)
__global__ __launch_bounds__(256) void reduce_kv(
    const float* __restrict__ Kp, const float* __restrict__ Vp,
    float* __restrict__ K32, float* __restrict__ V32) {
  const int i = blockIdx.x * 256 + threadIdx.x;  // < 262144
  float sk = 0.f, sv = 0.f;
#pragma unroll
  for (int z = 0; z < 16; ++z) {
    sk += Kp[(long long)z * 262144 + i];
    sv += Vp[(long long)z * 262144 + i];
  }
  K32[i] = sk;
  V32[i] = sv;
}

__global__ __launch_bounds__(256) void cast_kv(const float* __restrict__ K32,
                                               const float* __restrict__ V32,
                                               bfu* __restrict__ Kb, bfu* __restrict__ VTb) {
  int idx = blockIdx.x * 256 + threadIdx.x;
  int a = idx >> 9, b = idx & 511;
  Kb[idx] = f2b(K32[idx]);
  VTb[idx] = f2b(V32[b * 512 + a]);
}

__global__ __launch_bounds__(256) void cvec_k(const float* __restrict__ K32,
                                              const float* __restrict__ bq,
                                              float* __restrict__ cb) {
  const int lane = threadIdx.x & 63;
  const int w = blockIdx.x * 4 + (threadIdx.x >> 6);
  const int h = w >> 9, a = w & 511;
  float s = 0.f;
#pragma unroll
  for (int i = 0; i < 8; ++i) {
    int q = i * 64 + lane;
    s += K32[a * 512 + q] * bq[h * 512 + q];
  }
#pragma unroll
  for (int off = 32; off; off >>= 1) s += __shfl_xor(s, off, 64);
  if (lane == 0) cb[w] = s;
}

extern "C" void kernel_launch(void* const* d_in, const int* in_sizes, int n_in,
                              void* d_out, int out_size, void* d_ws, size_t ws_size,
                              hipStream_t stream) {
  (void)in_sizes; (void)n_in;
  const float* X    = (const float*)d_in[0];  // [8192,512]
  const float* enc0 = (const float*)d_in[1];  // [512,8192]
  const float* enc1 = (const float*)d_in[2];  // [512,8192]
  const float* Wq   = (const float*)d_in[3];  // [8,512,512]
  const float* bq   = (const float*)d_in[4];  // [8,512]
  const float* Wc   = (const float*)d_in[5];  // [512,4096]
  const float* bc   = (const float*)d_in[6];  // [512]
  float* out = (float*)d_out;                 // [8192,512] f32

  const size_t NEED = 83902464;  // 80.02 MB (unchanged)
  if (ws_size < NEED) {
    zero_out_k<<<dim3((out_size + 255) / 256), 256, 0, stream>>>(out, out_size);
    return;
  }
  char* w = (char*)d_ws;
  // Ecat (64 MB) overlays ALL transients below 67108864 (all dead before the
  // gemm_sme launch).
  bfu*   Ecat  = (bfu*)(w + 0);           // [8192][4096] 64 MB
  bfu*   XTb   = (bfu*)(w + 0);           // [512][8192]   8 MB (dead after KV)
  bfu*   enc0b = (bfu*)(w + 8388608);     // [512][8192]   8 MB (dead after KV)
  bfu*   enc1b = (bfu*)(w + 16777216);    // [512][8192]   8 MB (dead after KV)
  float* Kp32  = (float*)(w + 25165824);  // [16][512][512] 16 MB (dead after reduce)
  float* Vp32  = (float*)(w + 41943040);  // [16][512][512] 16 MB (dead after reduce)
  bfu*   WqTb  = (bfu*)(w + 58720256);    // [8][512][512]  4 MB (dead after M-gemm)
  bfu*   Wcb   = (bfu*)(w + 62914560);    // [512][4096]    4 MB (dead after N-gemm)
  // K32.. reuse the dead XTb slab (written by reduce_kv AFTER KV gemms):
  float* K32   = (float*)(w + 0);         // [512][512]    1 MB
  float* V32   = (float*)(w + 1048576);   // [512][512]    1 MB
  bfu*   Kb    = (bfu*)(w + 2097152);     // [512][512]  0.5 MB
  bfu*   VTb   = (bfu*)(w + 2621440);     // [512][512]  0.5 MB
  // persistent tail:
  bfu*   Xb    = (bfu*)(w + 67108864);    // [8192][512]   8 MB
  bfu*   Mb    = (bfu*)(w + 75497472);    // [8][512][512] 4 MB (dead after sme)
  float* invD2 = (float*)(w + 75497472);  // [8][8192] 256 KB, overlays dead Mb
  bfu*   Ncat  = (bfu*)(w + 79691776);    // [512][4096]   4 MB
  float* cb    = (float*)(w + 83886080);  // [8][512]     16 KB
  // ddp scratch lives in d_out (dead until gemm_fin, which only writes it):
  float* ddp   = out;                     // [8192][8][4]  1 MB

  conv_mat<<<dim3(4096), 256, 0, stream>>>(enc0, enc0b, 1048576);
  conv_mat<<<dim3(4096), 256, 0, stream>>>(enc1, enc1b, 1048576);
  conv_mat<<<dim3(2048), 256, 0, stream>>>(Wc, Wcb, 524288);

  dim3 tb(32, 8, 1);
  convT_x<<<dim3(16, 256, 1), tb, 0, stream>>>(X, Xb, XTb, 8192, 512);
  transpose_k<<<dim3(16, 16, 8), tb, 0, stream>>>(Wq, WqTb, 512, 512);

  // K = enc0 @ X, V = enc1 @ X: split-K=16 into f32 partial buffers (no atomics)
  gemm64p<3><<<dim3(4, 8, 16), 256, 0, stream>>>(enc0b, XTb, Kp32,
      8192, 8192, 512, 0, 0, 262144, 512, 1);
  gemm64p<3><<<dim3(4, 8, 16), 256, 0, stream>>>(enc1b, XTb, Vp32,
      8192, 8192, 512, 0, 0, 262144, 512, 1);
  reduce_kv<<<dim3(1024), 256, 0, stream>>>(Kp32, Vp32, K32, V32);
  cast_kv<<<dim3(1024), 256, 0, stream>>>(K32, V32, Kb, VTb);
  cvec_k<<<dim3(1024), 256, 0, stream>>>(K32, bq, cb);

  // M_h = K @ Wq_h
  gemm64p<1><<<dim3(4, 8, 8), 256, 0, stream>>>(Kb, WqTb, Mb,
      512, 512, 512, 0, 262144, 262144, 512, 0);
  // N_h = Wc_h @ V -> Ncat[o][h*512+a]
  gemm64p<1><<<dim3(4, 8, 8), 256, 0, stream>>>(Wcb, VTb, Ncat,
      4096, 512, 4096, 512, 0, 512, 512, 0);

  // fused logits+exp -> Ecat (unnormalized) + row-sum partials -> ddp
  gemm_sme<<<dim3(2048), 256, 0, stream>>>(Xb, Mb, Ecat, cb, ddp);
  inv_k<<<dim3(256), 256, 0, stream>>>(ddp, invD2);

  // out = bc + sum_h (Ecat_h @ Ncat_h^T) / D_h
  gemm_fin<<<dim3(512), 256, 0, stream>>>(Ecat, Ncat, out, bc, invD2);
}

// Round 7
// 273.200 us; speedup vs baseline: 1.1294x; 1.1294x over previous
//
#include <hip/hip_runtime.h>
#include <stdint.h>

typedef unsigned short bfu;
typedef __attribute__((ext_vector_type(8))) short bf16x8;   // MFMA A/B frag
typedef __attribute__((ext_vector_type(4))) float f32x4;    // MFMA C/D frag

__device__ __forceinline__ bfu f2b(float f) {
  unsigned int i = __builtin_bit_cast(unsigned int, f);
  i += 0x7FFFu + ((i >> 16) & 1u);  // round-to-nearest-even
  return (bfu)(i >> 16);
}
__device__ __forceinline__ float b2f(bfu b) {
  return __builtin_bit_cast(float, ((unsigned int)b) << 16);
}

// async global->LDS, 16B per lane. LDS dest must be wave-uniform base + lane*16.
__device__ __forceinline__ void stage16(const bfu* g, bfu* l) {
  __builtin_amdgcn_global_load_lds(
      (const __attribute__((address_space(1))) void*)g,
      (__attribute__((address_space(3))) void*)l, 16, 0, 0);
}

// ---------------------------------------------------------------------------
// C[M,N] = A[M,K] @ B[N,K]^T. 64x128 tile, BK=64.
// Prefetch double-buffered, T2 XOR-swizzled LDS. 4 waves 2x2 (acc[2][4]).
// MODE 1: store bf16 via LDS repack. MODE 3: store f32 (split-K partials via
// blockIdx.z when zIsK: k0 = z*Klen, cOff = z*sC).
template <int MODE>
__global__ __launch_bounds__(256) void gemm64p(
    const bfu* __restrict__ A, const bfu* __restrict__ B, void* __restrict__ Cv,
    int lda, int ldb, int ldc,
    long long sA, long long sB, long long sC,
    int Klen, int zIsK) {
  __shared__ __align__(16) bfu S[24576];
  const int tid = threadIdx.x;
  const int lane = tid & 63;
  const int wid = tid >> 6;
  const int l15 = lane & 15, l4 = lane >> 4;
  const int wm = wid >> 1, wn = wid & 1;

  int k0 = 0;
  long long cOff = 0;
  if (zIsK) {
    k0 = blockIdx.z * Klen;
    cOff = (long long)blockIdx.z * sC;
  } else {
    A += (long long)blockIdx.z * sA;
    B += (long long)blockIdx.z * sB;
    cOff = (long long)blockIdx.z * sC;
  }
  const int m0 = blockIdx.y * 64;
  const int n0 = blockIdx.x * 128;
  const bfu* Ag = A + (long long)m0 * lda + k0;
  const bfu* Bg = B + (long long)n0 * ldb + k0;

  f32x4 acc[2][4];
  const f32x4 zero = {0.f, 0.f, 0.f, 0.f};
#pragma unroll
  for (int r = 0; r < 2; ++r)
#pragma unroll
    for (int c = 0; c < 4; ++c) acc[r][c] = zero;

  const int lrow = lane >> 3;
  const int ldst = (lane & 7) * 8;
  const int lsrc = ldst ^ (lrow * 8);
  const int ksw = (l15 & 7) * 8;

  const int nIter = Klen >> 6;

  auto STAGE = [&](int kt, bfu* buf) {
    const bfu* Ak = Ag + kt * 64;
    const bfu* Bk = Bg + kt * 64;
#pragma unroll
    for (int j = 0; j < 2; ++j) {
      const int row = (wid * 2 + j) * 8 + lrow;
      stage16(Ak + (long long)row * lda + lsrc, buf + row * 64 + ldst);
    }
#pragma unroll
    for (int j = 0; j < 4; ++j) {
      const int row = (wid * 4 + j) * 8 + lrow;
      stage16(Bk + (long long)row * ldb + lsrc, buf + 4096 + row * 64 + ldst);
    }
  };

  STAGE(0, S);
  asm volatile("s_waitcnt vmcnt(0)" ::: "memory");
  __builtin_amdgcn_s_barrier();

  int cur = 0;
  for (int kt = 0; kt < nIter; ++kt) {
    bfu* bufc = S + (cur ? 12288 : 0);
    bfu* bufn = S + (cur ? 0 : 12288);
    if (kt + 1 < nIter) STAGE(kt + 1, bufn);
#pragma unroll
    for (int kk = 0; kk < 2; ++kk) {
      const int ko = (kk * 32 + l4 * 8) ^ ksw;
      bf16x8 af[2], bfr[4];
#pragma unroll
      for (int r = 0; r < 2; ++r)
        af[r] = *(const bf16x8*)(bufc + (wm * 32 + r * 16 + l15) * 64 + ko);
#pragma unroll
      for (int c = 0; c < 4; ++c)
        bfr[c] = *(const bf16x8*)(bufc + 4096 + (wn * 64 + c * 16 + l15) * 64 + ko);
#pragma unroll
      for (int r = 0; r < 2; ++r)
#pragma unroll
        for (int c = 0; c < 4; ++c)
          acc[r][c] = __builtin_amdgcn_mfma_f32_16x16x32_bf16(af[r], bfr[c], acc[r][c], 0, 0, 0);
    }
    asm volatile("s_waitcnt vmcnt(0)" ::: "memory");
    __builtin_amdgcn_s_barrier();
    cur ^= 1;
  }

  if (MODE == 3) {
    float* Cf = (float*)Cv;
#pragma unroll
    for (int r = 0; r < 2; ++r) {
#pragma unroll
      for (int c = 0; c < 4; ++c) {
        const int gr = m0 + wm * 32 + r * 16 + (l4 << 2);
        const int gc = n0 + wn * 64 + c * 16 + l15;
#pragma unroll
        for (int v = 0; v < 4; ++v)
          Cf[cOff + (long long)(gr + v) * ldc + gc] = acc[r][c][v];
      }
    }
  } else {
    // bf16 epilogue: repack 64x128 C tile via LDS (XOR-swizzled), 16B stores.
#pragma unroll
    for (int r = 0; r < 2; ++r) {
#pragma unroll
      for (int c = 0; c < 4; ++c) {
        const int col = wn * 64 + c * 16 + l15;
#pragma unroll
        for (int v = 0; v < 4; ++v) {
          const int row = wm * 32 + r * 16 + (l4 << 2) + v;
          S[row * 128 + (col ^ (((row >> 2) & 3) << 4))] = f2b(acc[r][c][v]);
        }
      }
    }
    __syncthreads();
    bfu* Cb = (bfu*)Cv;
#pragma unroll
    for (int i = 0; i < 4; ++i) {
      const int j = i * 256 + tid;
      const int row = j >> 4;
      const int colbase = (j & 15) * 8;
      const int sc = colbase ^ (((row >> 2) & 3) << 4);
      uint4 val = *(const uint4*)(S + row * 128 + sc);
      *(uint4*)(Cb + cOff + (long long)(m0 + row) * ldc + n0 + colbase) = val;
    }
  }
}

// ---------------------------------------------------------------------------
// Fused logits+exp GEMM (round-4 gemm128p structure, proven 50.5us, 2 blk/CU):
//   Ecat[s][h*512+a] = bf16(exp((X[s,:]@M_h[a,:]^T + cb[h,a]) / sqrt(512)))
// UNNORMALIZED (no max-sub: logits ~N(0,1.2), |x|<~6 -> exp in [2e-3, 4e2]).
// Register-light epilogue: exp applied INSIDE the repack loop (straight to
// LDS, no register array); row-sums computed FROM the stored uint4s in the
// store loop (16-lane shfl per row) -> ddp[s*32+h*4+bx]. Keeps VGPR at the
// round-4 GEMM profile so occupancy + L2 reuse are preserved.
__global__ __launch_bounds__(256) void gemm_sme(
    const bfu* __restrict__ Xb, const bfu* __restrict__ Mb,
    bfu* __restrict__ Ecat, const float* __restrict__ cb,
    float* __restrict__ ddp) {
  __shared__ __align__(16) bfu S[32768];  // 2 x (At 128x64 + Bt 128x64) = 64KB
  const int tid = threadIdx.x;
  const int lane = tid & 63;
  const int wid = tid >> 6;
  const int l15 = lane & 15, l4 = lane >> 4;
  const int wm = wid >> 1, wn = wid & 1;

  // XCD swizzle: nwg=2048, chunk=256; y-major decode.
  const int bid = blockIdx.x;
  const int swz = ((bid & 7) << 8) + (bid >> 3);
  const int by = swz >> 5;        // m-panel 0..63
  const int h  = (swz >> 2) & 7;  // head
  const int bx = swz & 3;         // n-block

  const int m0 = by * 128;
  const int n0l = bx * 128;       // col-block within head
  const bfu* Ag = Xb + (long long)m0 * 512;
  const bfu* Bg = Mb + (long long)h * 262144 + (long long)n0l * 512;

  f32x4 acc[4][4];
  const f32x4 zero = {0.f, 0.f, 0.f, 0.f};
#pragma unroll
  for (int r = 0; r < 4; ++r)
#pragma unroll
    for (int c = 0; c < 4; ++c) acc[r][c] = zero;

  const int lrow = lane >> 3;
  const int ldst = (lane & 7) * 8;
  const int lsrc = ldst ^ (lrow * 8);
  const int ksw = (l15 & 7) * 8;

  auto STAGE = [&](int kt, bfu* buf) {
    const bfu* Ak = Ag + kt * 64;
    const bfu* Bk = Bg + kt * 64;
#pragma unroll
    for (int j = 0; j < 4; ++j) {
      const int row = (wid * 4 + j) * 8 + lrow;
      stage16(Ak + (long long)row * 512 + lsrc, buf + row * 64 + ldst);
    }
#pragma unroll
    for (int j = 0; j < 4; ++j) {
      const int row = (wid * 4 + j) * 8 + lrow;
      stage16(Bk + (long long)row * 512 + lsrc, buf + 8192 + row * 64 + ldst);
    }
  };

  STAGE(0, S);
  asm volatile("s_waitcnt vmcnt(0)" ::: "memory");
  __builtin_amdgcn_s_barrier();

  for (int kt = 0; kt < 8; ++kt) {   // K = 512
    bfu* bufc = S + ((kt & 1) ? 16384 : 0);
    bfu* bufn = S + ((kt & 1) ? 0 : 16384);
    if (kt + 1 < 8) STAGE(kt + 1, bufn);
#pragma unroll
    for (int kk = 0; kk < 2; ++kk) {
      const int ko = (kk * 32 + l4 * 8) ^ ksw;
      bf16x8 af[4], bfr[4];
#pragma unroll
      for (int r = 0; r < 4; ++r)
        af[r] = *(const bf16x8*)(bufc + (wm * 64 + r * 16 + l15) * 64 + ko);
#pragma unroll
      for (int c = 0; c < 4; ++c)
        bfr[c] = *(const bf16x8*)(bufc + 8192 + (wn * 64 + c * 16 + l15) * 64 + ko);
#pragma unroll
      for (int r = 0; r < 4; ++r)
#pragma unroll
        for (int c = 0; c < 4; ++c)
          acc[r][c] = __builtin_amdgcn_mfma_f32_16x16x32_bf16(af[r], bfr[c], acc[r][c], 0, 0, 0);
    }
    asm volatile("s_waitcnt vmcnt(0)" ::: "memory");
    __builtin_amdgcn_s_barrier();
  }

  // ---- repack with exp fused (XOR-swizzled); no register-resident results ----
  const float scale = 0.044194173824159216f;  // 1/sqrt(512)
  float ch[4];
#pragma unroll
  for (int c = 0; c < 4; ++c)
    ch[c] = cb[h * 512 + n0l + wn * 64 + c * 16 + l15];
#pragma unroll
  for (int r = 0; r < 4; ++r)
#pragma unroll
    for (int c = 0; c < 4; ++c) {
      const int col = wn * 64 + c * 16 + l15;
#pragma unroll
      for (int v = 0; v < 4; ++v) {
        const int row = wm * 64 + r * 16 + (l4 << 2) + v;
        S[row * 128 + (col ^ (((row >> 2) & 3) << 4))] =
            f2b(__expf((acc[r][c][v] + ch[c]) * scale));
      }
    }
  __syncthreads();

  // ---- store + row-sum from the stored (bf16-rounded) values ----
  // Row j>>4 is handled by 16 consecutive tids (an aligned 16-lane subgroup):
  // shfl_xor width<16 stays inside it. Lane (tid&15)==0 writes ddp.
#pragma unroll
  for (int i = 0; i < 8; ++i) {
    const int j = i * 256 + tid;
    const int row = j >> 4;            // 0..127
    const int colbase = (j & 15) * 8;  // 0..120
    const int sc = colbase ^ (((row >> 2) & 3) << 4);
    union { uint4 u; bfu us[8]; } pk;
    pk.u = *(const uint4*)(S + row * 128 + sc);
    *(uint4*)(Ecat + (long long)(m0 + row) * 4096 + h * 512 + n0l + colbase) = pk.u;
    float s = 0.f;
#pragma unroll
    for (int e = 0; e < 8; ++e) s += b2f(pk.us[e]);
#pragma unroll
    for (int off = 1; off < 16; off <<= 1) s += __shfl_xor(s, off, 64);
    if ((tid & 15) == 0)
      ddp[(long long)(m0 + row) * 32 + h * 4 + bx] = s;
  }
}

// invD2[h*8192 + s] = 1 / sum_bx ddp[s*32 + h*4 + bx]
__global__ __launch_bounds__(256) void inv_k(const float* __restrict__ ddp,
                                             float* __restrict__ invD2) {
  const int i = blockIdx.x * 256 + threadIdx.x;  // s*8+h, 65536 total
  f32x4 p = *(const f32x4*)(ddp + (long long)i * 4);
  const int s = i >> 3, h = i & 7;
  invD2[h * 8192 + s] = 1.0f / (p[0] + p[1] + p[2] + p[3]);
}

// ---------------------------------------------------------------------------
// Final GEMM with per-head normalization:
//   out[s][o] = bias[o] + sum_h (1/D[h][s]) * sum_a expE[s][h*512+a]*Ncat[o][h*512+a]
// 64x128 tile, 512 blocks (2/CU), PIPE=3 counted vmcnt, XCD swizzle.
// invD2 preloaded BEFORE staging (drained so vmcnt counts stay clean);
// consumed via static register rotation (no runtime array indexing).
__global__ __launch_bounds__(256) void gemm_fin(
    const bfu* __restrict__ A, const bfu* __restrict__ B, float* __restrict__ C,
    const float* __restrict__ bias, const float* __restrict__ invD2) {
  __shared__ __align__(16) bfu S[36864];  // 3 x 24KB
  const int tid = threadIdx.x;
  const int lane = tid & 63;
  const int wid = tid >> 6;
  const int l15 = lane & 15, l4 = lane >> 4;
  const int wm = wid >> 1, wn = wid & 1;

  const int bid = blockIdx.x;
  const int swz = ((bid & 7) << 6) + (bid >> 3);
  const int m0 = (swz >> 2) * 64;
  const int n0 = (swz & 3) * 128;
  const bfu* Ag = A + (long long)m0 * 4096;
  const bfu* Bg = B + (long long)n0 * 4096;

  // preload inverse denominators: rows m0+wm*32+{0,16}+l4*4+v, per head
  f32x4 inv0[8], inv1[8];
#pragma unroll
  for (int h = 0; h < 8; ++h) {
    const float* p = invD2 + h * 8192 + m0 + wm * 32 + (l4 << 2);
    inv0[h] = *(const f32x4*)p;
    inv1[h] = *(const f32x4*)(p + 16);
  }

  f32x4 macc[2][4], acc[2][4];
  const f32x4 zero = {0.f, 0.f, 0.f, 0.f};
#pragma unroll
  for (int r = 0; r < 2; ++r)
#pragma unroll
    for (int c = 0; c < 4; ++c) { macc[r][c] = zero; acc[r][c] = zero; }

  const int lrow = lane >> 3;
  const int ldst = (lane & 7) * 8;
  const int lsrc = ldst ^ (lrow * 8);
  const int ksw = (l15 & 7) * 8;

  auto STAGE = [&](int kt, bfu* buf) {  // 6 gload_lds per lane
    const bfu* Ak = Ag + kt * 64;
    const bfu* Bk = Bg + kt * 64;
#pragma unroll
    for (int j = 0; j < 2; ++j) {
      const int row = (wid * 2 + j) * 8 + lrow;
      stage16(Ak + (long long)row * 4096 + lsrc, buf + row * 64 + ldst);
    }
#pragma unroll
    for (int j = 0; j < 4; ++j) {
      const int row = (wid * 4 + j) * 8 + lrow;
      stage16(Bk + (long long)row * 4096 + lsrc, buf + 4096 + row * 64 + ldst);
    }
  };

  // drain preloads so staged-load counting below is exact
  asm volatile("s_waitcnt vmcnt(0)" ::: "memory");

  STAGE(0, S);
  STAGE(1, S + 12288);

  for (int kt = 0; kt < 64; ++kt) {   // K = 4096
    if (kt > 0) __builtin_amdgcn_s_barrier();
    if (kt + 2 < 64) STAGE(kt + 2, S + 12288 * ((kt + 2) % 3));
    const int rem = 63 - kt;
    if (rem >= 2)
      asm volatile("s_waitcnt vmcnt(12)" ::: "memory");
    else if (rem == 1)
      asm volatile("s_waitcnt vmcnt(6)" ::: "memory");
    else
      asm volatile("s_waitcnt vmcnt(0)" ::: "memory");
    __builtin_amdgcn_s_barrier();

    const bfu* bufc = S + 12288 * (kt % 3);
#pragma unroll
    for (int kk = 0; kk < 2; ++kk) {
      const int ko = (kk * 32 + l4 * 8) ^ ksw;
      bf16x8 af[2], bfr[4];
#pragma unroll
      for (int r = 0; r < 2; ++r)
        af[r] = *(const bf16x8*)(bufc + (wm * 32 + r * 16 + l15) * 64 + ko);
#pragma unroll
      for (int c = 0; c < 4; ++c)
        bfr[c] = *(const bf16x8*)(bufc + 4096 + (wn * 64 + c * 16 + l15) * 64 + ko);
#pragma unroll
      for (int r = 0; r < 2; ++r)
#pragma unroll
        for (int c = 0; c < 4; ++c)
          acc[r][c] = __builtin_amdgcn_mfma_f32_16x16x32_bf16(af[r], bfr[c], acc[r][c], 0, 0, 0);
    }

    if ((kt & 7) == 7) {  // head boundary: fold seg into master with 1/D
#pragma unroll
      for (int r = 0; r < 2; ++r) {
        const f32x4 iv = r ? inv1[0] : inv0[0];
#pragma unroll
        for (int c = 0; c < 4; ++c) {
#pragma unroll
          for (int v = 0; v < 4; ++v) macc[r][c][v] += acc[r][c][v] * iv[v];
          acc[r][c] = zero;
        }
      }
#pragma unroll
      for (int q = 0; q < 7; ++q) { inv0[q] = inv0[q + 1]; inv1[q] = inv1[q + 1]; }
    }
  }

  // f32 + bias store
#pragma unroll
  for (int r = 0; r < 2; ++r) {
#pragma unroll
    for (int c = 0; c < 4; ++c) {
      const int gr = m0 + wm * 32 + r * 16 + (l4 << 2);
      const int gc = n0 + wn * 64 + c * 16 + l15;
      const float bval = bias[gc];
#pragma unroll
      for (int v = 0; v < 4; ++v)
        C[(long long)(gr + v) * 512 + gc] = macc[r][c][v] + bval;
    }
  }
}

// ---------------- helpers ----------------
__global__ void convT_x(const float* __restrict__ in, bfu* __restrict__ outN,
                        bfu* __restrict__ outT, int R, int C) {
  __shared__ bfu t[32][33];
  const int c0 = blockIdx.x * 32, r0 = blockIdx.y * 32;
  const int tx = threadIdx.x, ty = threadIdx.y;
  for (int i = ty; i < 32; i += 8) {
    bfu b = f2b(in[(long long)(r0 + i) * C + (c0 + tx)]);
    outN[(long long)(r0 + i) * C + (c0 + tx)] = b;
    t[i][tx] = b;
  }
  __syncthreads();
  for (int i = ty; i < 32; i += 8)
    outT[(long long)(c0 + i) * R + (r0 + tx)] = t[tx][i];
}

__global__ void transpose_k(const float* __restrict__ in, bfu* __restrict__ out,
                            int R, int C) {
  __shared__ bfu t[32][33];
  const long long boff = (long long)blockIdx.z * R * C;
  const int c0 = blockIdx.x * 32, r0 = blockIdx.y * 32;
  const int tx = threadIdx.x, ty = threadIdx.y;
  for (int i = ty; i < 32; i += 8)
    t[i][tx] = f2b(in[boff + (long long)(r0 + i) * C + (c0 + tx)]);
  __syncthreads();
  for (int i = ty; i < 32; i += 8)
    out[boff + (long long)(c0 + i) * R + (r0 + tx)] = t[tx][i];
}

__global__ __launch_bounds__(256) void conv_mat(const float* __restrict__ src,
                                                bfu* __restrict__ dst, int count4) {
  int i = blockIdx.x * 256 + threadIdx.x;
  if (i < count4) {
    float4 f = ((const float4*)src)[i];
    ushort4 o;
    o.x = f2b(f.x); o.y = f2b(f.y); o.z = f2b(f.z); o.w = f2b(f.w);
    ((ushort4*)dst)[i] = o;
  }
}

__global__ __launch_bounds__(256) void zero_out_k(float* __restrict__ p, int n) {
  int i = blockIdx.x * 256 + threadIdx.x;
  if (i < n) p[i] = 0.f;
}

// K32[i] = sum_z Kp[z][i]; V32 likewise (replaces split-K atomics)
__global__ __launch_bounds__(256) void reduce_kv(
    const float* __restrict__ Kp, const float* __restrict__ Vp,
    float* __restrict__ K32, float* __restrict__ V32) {
  const int i = blockIdx.x * 256 + threadIdx.x;  // < 262144
  float sk = 0.f, sv = 0.f;
#pragma unroll
  for (int z = 0; z < 16; ++z) {
    sk += Kp[(long long)z * 262144 + i];
    sv += Vp[(long long)z * 262144 + i];
  }
  K32[i] = sk;
  V32[i] = sv;
}

__global__ __launch_bounds__(256) void cast_kv(const float* __restrict__ K32,
                                               const float* __restrict__ V32,
                                               bfu* __restrict__ Kb, bfu* __restrict__ VTb) {
  int idx = blockIdx.x * 256 + threadIdx.x;
  int a = idx >> 9, b = idx & 511;
  Kb[idx] = f2b(K32[idx]);
  VTb[idx] = f2b(V32[b * 512 + a]);
}

__global__ __launch_bounds__(256) void cvec_k(const float* __restrict__ K32,
                                              const float* __restrict__ bq,
                                              float* __restrict__ cb) {
  const int lane = threadIdx.x & 63;
  const int w = blockIdx.x * 4 + (threadIdx.x >> 6);
  const int h = w >> 9, a = w & 511;
  float s = 0.f;
#pragma unroll
  for (int i = 0; i < 8; ++i) {
    int q = i * 64 + lane;
    s += K32[a * 512 + q] * bq[h * 512 + q];
  }
#pragma unroll
  for (int off = 32; off; off >>= 1) s += __shfl_xor(s, off, 64);
  if (lane == 0) cb[w] = s;
}

extern "C" void kernel_launch(void* const* d_in, const int* in_sizes, int n_in,
                              void* d_out, int out_size, void* d_ws, size_t ws_size,
                              hipStream_t stream) {
  (void)in_sizes; (void)n_in;
  const float* X    = (const float*)d_in[0];  // [8192,512]
  const float* enc0 = (const float*)d_in[1];  // [512,8192]
  const float* enc1 = (const float*)d_in[2];  // [512,8192]
  const float* Wq   = (const float*)d_in[3];  // [8,512,512]
  const float* bq   = (const float*)d_in[4];  // [8,512]
  const float* Wc   = (const float*)d_in[5];  // [512,4096]
  const float* bc   = (const float*)d_in[6];  // [512]
  float* out = (float*)d_out;                 // [8192,512] f32

  const size_t NEED = 83902464;  // 80.02 MB (unchanged)
  if (ws_size < NEED) {
    zero_out_k<<<dim3((out_size + 255) / 256), 256, 0, stream>>>(out, out_size);
    return;
  }
  char* w = (char*)d_ws;
  // Ecat (64 MB) overlays ALL transients below 67108864 (all dead before the
  // gemm_sme launch).
  bfu*   Ecat  = (bfu*)(w + 0);           // [8192][4096] 64 MB
  bfu*   XTb   = (bfu*)(w + 0);           // [512][8192]   8 MB (dead after KV)
  bfu*   enc0b = (bfu*)(w + 8388608);     // [512][8192]   8 MB (dead after KV)
  bfu*   enc1b = (bfu*)(w + 16777216);    // [512][8192]   8 MB (dead after KV)
  float* Kp32  = (float*)(w + 25165824);  // [16][512][512] 16 MB (dead after reduce)
  float* Vp32  = (float*)(w + 41943040);  // [16][512][512] 16 MB (dead after reduce)
  bfu*   WqTb  = (bfu*)(w + 58720256);    // [8][512][512]  4 MB (dead after M-gemm)
  bfu*   Wcb   = (bfu*)(w + 62914560);    // [512][4096]    4 MB (dead after N-gemm)
  // K32.. reuse the dead XTb slab (written by reduce_kv AFTER KV gemms):
  float* K32   = (float*)(w + 0);         // [512][512]    1 MB
  float* V32   = (float*)(w + 1048576);   // [512][512]    1 MB
  bfu*   Kb    = (bfu*)(w + 2097152);     // [512][512]  0.5 MB
  bfu*   VTb   = (bfu*)(w + 2621440);     // [512][512]  0.5 MB
  // persistent tail:
  bfu*   Xb    = (bfu*)(w + 67108864);    // [8192][512]   8 MB
  bfu*   Mb    = (bfu*)(w + 75497472);    // [8][512][512] 4 MB (dead after sme)
  float* invD2 = (float*)(w + 75497472);  // [8][8192] 256 KB, overlays dead Mb
  bfu*   Ncat  = (bfu*)(w + 79691776);    // [512][4096]   4 MB
  float* cb    = (float*)(w + 83886080);  // [8][512]     16 KB
  // ddp scratch lives in d_out (dead until gemm_fin, which only writes it):
  float* ddp   = out;                     // [8192][8][4]  1 MB

  conv_mat<<<dim3(4096), 256, 0, stream>>>(enc0, enc0b, 1048576);
  conv_mat<<<dim3(4096), 256, 0, stream>>>(enc1, enc1b, 1048576);
  conv_mat<<<dim3(2048), 256, 0, stream>>>(Wc, Wcb, 524288);

  dim3 tb(32, 8, 1);
  convT_x<<<dim3(16, 256, 1), tb, 0, stream>>>(X, Xb, XTb, 8192, 512);
  transpose_k<<<dim3(16, 16, 8), tb, 0, stream>>>(Wq, WqTb, 512, 512);

  // K = enc0 @ X, V = enc1 @ X: split-K=16 into f32 partial buffers (no atomics)
  gemm64p<3><<<dim3(4, 8, 16), 256, 0, stream>>>(enc0b, XTb, Kp32,
      8192, 8192, 512, 0, 0, 262144, 512, 1);
  gemm64p<3><<<dim3(4, 8, 16), 256, 0, stream>>>(enc1b, XTb, Vp32,
      8192, 8192, 512, 0, 0, 262144, 512, 1);
  reduce_kv<<<dim3(1024), 256, 0, stream>>>(Kp32, Vp32, K32, V32);
  cast_kv<<<dim3(1024), 256, 0, stream>>>(K32, V32, Kb, VTb);
  cvec_k<<<dim3(1024), 256, 0, stream>>>(K32, bq, cb);

  // M_h = K @ Wq_h
  gemm64p<1><<<dim3(4, 8, 8), 256, 0, stream>>>(Kb, WqTb, Mb,
      512, 512, 512, 0, 262144, 262144, 512, 0);
  // N_h = Wc_h @ V -> Ncat[o][h*512+a]
  gemm64p<1><<<dim3(4, 8, 8), 256, 0, stream>>>(Wcb, VTb, Ncat,
      4096, 512, 4096, 512, 0, 512, 512, 0);

  // fused logits+exp -> Ecat (unnormalized) + row-sum partials -> ddp
  gemm_sme<<<dim3(2048), 256, 0, stream>>>(Xb, Mb, Ecat, cb, ddp);
  inv_k<<<dim3(256), 256, 0, stream>>>(ddp, invD2);

  // out = bc + sum_h (Ecat_h @ Ncat_h^T) / D_h
  gemm_fin<<<dim3(512), 256, 0, stream>>>(Ecat, Ncat, out, bc, invD2);
}

// Round 8
// 265.559 us; speedup vs baseline: 1.1619x; 1.0288x over previous
//
#include <hip/hip_runtime.h>
#include <stdint.h>

typedef unsigned short bfu;
typedef __attribute__((ext_vector_type(8))) short bf16x8;   // MFMA A/B frag
typedef __attribute__((ext_vector_type(4))) float f32x4;    // MFMA C/D frag

__device__ __forceinline__ bfu f2b(float f) {
  unsigned int i = __builtin_bit_cast(unsigned int, f);
  i += 0x7FFFu + ((i >> 16) & 1u);  // round-to-nearest-even
  return (bfu)(i >> 16);
}
__device__ __forceinline__ float b2f(bfu b) {
  return __builtin_bit_cast(float, ((unsigned int)b) << 16);
}

// async global->LDS, 16B per lane. LDS dest must be wave-uniform base + lane*16.
__device__ __forceinline__ void stage16(const bfu* g, bfu* l) {
  __builtin_amdgcn_global_load_lds(
      (const __attribute__((address_space(1))) void*)g,
      (__attribute__((address_space(3))) void*)l, 16, 0, 0);
}

// ---------------------------------------------------------------------------
// C[M,N] = A[M,K] @ B[N,K]^T. 64x128 tile, BK=64.
// Prefetch double-buffered, T2 XOR-swizzled LDS. 4 waves 2x2 (acc[2][4]).
// MODE 3: store f32 (split-K partials via blockIdx.z: k0=z*Klen, cOff=z*sC).
template <int MODE>
__global__ __launch_bounds__(256) void gemm64p(
    const bfu* __restrict__ A, const bfu* __restrict__ B, void* __restrict__ Cv,
    int lda, int ldb, int ldc,
    long long sA, long long sB, long long sC,
    int Klen, int zIsK) {
  __shared__ __align__(16) bfu S[24576];
  const int tid = threadIdx.x;
  const int lane = tid & 63;
  const int wid = tid >> 6;
  const int l15 = lane & 15, l4 = lane >> 4;
  const int wm = wid >> 1, wn = wid & 1;

  int k0 = 0;
  long long cOff = 0;
  if (zIsK) {
    k0 = blockIdx.z * Klen;
    cOff = (long long)blockIdx.z * sC;
  } else {
    A += (long long)blockIdx.z * sA;
    B += (long long)blockIdx.z * sB;
    cOff = (long long)blockIdx.z * sC;
  }
  const int m0 = blockIdx.y * 64;
  const int n0 = blockIdx.x * 128;
  const bfu* Ag = A + (long long)m0 * lda + k0;
  const bfu* Bg = B + (long long)n0 * ldb + k0;

  f32x4 acc[2][4];
  const f32x4 zero = {0.f, 0.f, 0.f, 0.f};
#pragma unroll
  for (int r = 0; r < 2; ++r)
#pragma unroll
    for (int c = 0; c < 4; ++c) acc[r][c] = zero;

  const int lrow = lane >> 3;
  const int ldst = (lane & 7) * 8;
  const int lsrc = ldst ^ (lrow * 8);
  const int ksw = (l15 & 7) * 8;

  const int nIter = Klen >> 6;

  auto STAGE = [&](int kt, bfu* buf) {
    const bfu* Ak = Ag + kt * 64;
    const bfu* Bk = Bg + kt * 64;
#pragma unroll
    for (int j = 0; j < 2; ++j) {
      const int row = (wid * 2 + j) * 8 + lrow;
      stage16(Ak + (long long)row * lda + lsrc, buf + row * 64 + ldst);
    }
#pragma unroll
    for (int j = 0; j < 4; ++j) {
      const int row = (wid * 4 + j) * 8 + lrow;
      stage16(Bk + (long long)row * ldb + lsrc, buf + 4096 + row * 64 + ldst);
    }
  };

  STAGE(0, S);
  asm volatile("s_waitcnt vmcnt(0)" ::: "memory");
  __builtin_amdgcn_s_barrier();

  int cur = 0;
  for (int kt = 0; kt < nIter; ++kt) {
    bfu* bufc = S + (cur ? 12288 : 0);
    bfu* bufn = S + (cur ? 0 : 12288);
    if (kt + 1 < nIter) STAGE(kt + 1, bufn);
#pragma unroll
    for (int kk = 0; kk < 2; ++kk) {
      const int ko = (kk * 32 + l4 * 8) ^ ksw;
      bf16x8 af[2], bfr[4];
#pragma unroll
      for (int r = 0; r < 2; ++r)
        af[r] = *(const bf16x8*)(bufc + (wm * 32 + r * 16 + l15) * 64 + ko);
#pragma unroll
      for (int c = 0; c < 4; ++c)
        bfr[c] = *(const bf16x8*)(bufc + 4096 + (wn * 64 + c * 16 + l15) * 64 + ko);
#pragma unroll
      for (int r = 0; r < 2; ++r)
#pragma unroll
        for (int c = 0; c < 4; ++c)
          acc[r][c] = __builtin_amdgcn_mfma_f32_16x16x32_bf16(af[r], bfr[c], acc[r][c], 0, 0, 0);
    }
    asm volatile("s_waitcnt vmcnt(0)" ::: "memory");
    __builtin_amdgcn_s_barrier();
    cur ^= 1;
  }

  if (MODE == 3) {
    float* Cf = (float*)Cv;
#pragma unroll
    for (int r = 0; r < 2; ++r) {
#pragma unroll
      for (int c = 0; c < 4; ++c) {
        const int gr = m0 + wm * 32 + r * 16 + (l4 << 2);
        const int gc = n0 + wn * 64 + c * 16 + l15;
#pragma unroll
        for (int v = 0; v < 4; ++v)
          Cf[cOff + (long long)(gr + v) * ldc + gc] = acc[r][c][v];
      }
    }
  } else {
    // bf16 epilogue: repack 64x128 C tile via LDS (XOR-swizzled), 16B stores.
#pragma unroll
    for (int r = 0; r < 2; ++r) {
#pragma unroll
      for (int c = 0; c < 4; ++c) {
        const int col = wn * 64 + c * 16 + l15;
#pragma unroll
        for (int v = 0; v < 4; ++v) {
          const int row = wm * 32 + r * 16 + (l4 << 2) + v;
          S[row * 128 + (col ^ (((row >> 2) & 3) << 4))] = f2b(acc[r][c][v]);
        }
      }
    }
    __syncthreads();
    bfu* Cb = (bfu*)Cv;
#pragma unroll
    for (int i = 0; i < 4; ++i) {
      const int j = i * 256 + tid;
      const int row = j >> 4;
      const int colbase = (j & 15) * 8;
      const int sc = colbase ^ (((row >> 2) & 3) << 4);
      uint4 val = *(const uint4*)(S + row * 128 + sc);
      *(uint4*)(Cb + cOff + (long long)(m0 + row) * ldc + n0 + colbase) = val;
    }
  }
}

// ---------------------------------------------------------------------------
// Merged M/N GEMM (both 512x512x512 per head; 512 blocks = 2/CU):
//   z<8 : M_h = Kb @ WqTb_h^T  -> Mb[h]
//   z>=8: N_h = Wcb[:,h*512:] @ VTb^T -> Ncat[:,h*512:]
// Same proven 2-phase body, bf16 repack epilogue.
__global__ __launch_bounds__(256) void gemm_mn(
    const bfu* __restrict__ Kb, const bfu* __restrict__ WqTb, bfu* __restrict__ Mbp,
    const bfu* __restrict__ Wcb, const bfu* __restrict__ VTb, bfu* __restrict__ Ncat) {
  __shared__ __align__(16) bfu S[24576];
  const int tid = threadIdx.x;
  const int lane = tid & 63;
  const int wid = tid >> 6;
  const int l15 = lane & 15, l4 = lane >> 4;
  const int wm = wid >> 1, wn = wid & 1;

  const int z = blockIdx.z;
  const bfu* A; const bfu* B; bfu* Cb; int lda, ldb, ldc; long long cOff;
  if (z < 8) {
    A = Kb;                               lda = 512;
    B = WqTb + (long long)z * 262144;     ldb = 512;
    Cb = Mbp;  ldc = 512;  cOff = (long long)z * 262144;
  } else {
    A = Wcb + (long long)(z - 8) * 512;   lda = 4096;
    B = VTb;                              ldb = 512;
    Cb = Ncat; ldc = 4096; cOff = (long long)(z - 8) * 512;
  }
  const int m0 = blockIdx.y * 64;
  const int n0 = blockIdx.x * 128;
  const bfu* Ag = A + (long long)m0 * lda;
  const bfu* Bg = B + (long long)n0 * ldb;

  f32x4 acc[2][4];
  const f32x4 zero = {0.f, 0.f, 0.f, 0.f};
#pragma unroll
  for (int r = 0; r < 2; ++r)
#pragma unroll
    for (int c = 0; c < 4; ++c) acc[r][c] = zero;

  const int lrow = lane >> 3;
  const int ldst = (lane & 7) * 8;
  const int lsrc = ldst ^ (lrow * 8);
  const int ksw = (l15 & 7) * 8;

  auto STAGE = [&](int kt, bfu* buf) {
    const bfu* Ak = Ag + kt * 64;
    const bfu* Bk = Bg + kt * 64;
#pragma unroll
    for (int j = 0; j < 2; ++j) {
      const int row = (wid * 2 + j) * 8 + lrow;
      stage16(Ak + (long long)row * lda + lsrc, buf + row * 64 + ldst);
    }
#pragma unroll
    for (int j = 0; j < 4; ++j) {
      const int row = (wid * 4 + j) * 8 + lrow;
      stage16(Bk + (long long)row * ldb + lsrc, buf + 4096 + row * 64 + ldst);
    }
  };

  STAGE(0, S);
  asm volatile("s_waitcnt vmcnt(0)" ::: "memory");
  __builtin_amdgcn_s_barrier();

  int cur = 0;
  for (int kt = 0; kt < 8; ++kt) {   // K = 512
    bfu* bufc = S + (cur ? 12288 : 0);
    bfu* bufn = S + (cur ? 0 : 12288);
    if (kt + 1 < 8) STAGE(kt + 1, bufn);
#pragma unroll
    for (int kk = 0; kk < 2; ++kk) {
      const int ko = (kk * 32 + l4 * 8) ^ ksw;
      bf16x8 af[2], bfr[4];
#pragma unroll
      for (int r = 0; r < 2; ++r)
        af[r] = *(const bf16x8*)(bufc + (wm * 32 + r * 16 + l15) * 64 + ko);
#pragma unroll
      for (int c = 0; c < 4; ++c)
        bfr[c] = *(const bf16x8*)(bufc + 4096 + (wn * 64 + c * 16 + l15) * 64 + ko);
#pragma unroll
      for (int r = 0; r < 2; ++r)
#pragma unroll
        for (int c = 0; c < 4; ++c)
          acc[r][c] = __builtin_amdgcn_mfma_f32_16x16x32_bf16(af[r], bfr[c], acc[r][c], 0, 0, 0);
    }
    asm volatile("s_waitcnt vmcnt(0)" ::: "memory");
    __builtin_amdgcn_s_barrier();
    cur ^= 1;
  }

  // bf16 repack epilogue
#pragma unroll
  for (int r = 0; r < 2; ++r) {
#pragma unroll
    for (int c = 0; c < 4; ++c) {
      const int col = wn * 64 + c * 16 + l15;
#pragma unroll
      for (int v = 0; v < 4; ++v) {
        const int row = wm * 32 + r * 16 + (l4 << 2) + v;
        S[row * 128 + (col ^ (((row >> 2) & 3) << 4))] = f2b(acc[r][c][v]);
      }
    }
  }
  __syncthreads();
#pragma unroll
  for (int i = 0; i < 4; ++i) {
    const int j = i * 256 + tid;
    const int row = j >> 4;
    const int colbase = (j & 15) * 8;
    const int sc = colbase ^ (((row >> 2) & 3) << 4);
    uint4 val = *(const uint4*)(S + row * 128 + sc);
    *(uint4*)(Cb + cOff + (long long)(m0 + row) * ldc + n0 + colbase) = val;
  }
}

// ---------------------------------------------------------------------------
// Fused logits+exp GEMM (proven round-7 structure; h-major XCD decode):
//   Ecat[s][h*512+a] = bf16(exp((X[s,:]@M_h[a,:]^T + cb[h,a]) / sqrt(512)))
// UNNORMALIZED (no max-sub: logits ~N(0,1.2)). Row-sum partials from the
// bf16-rounded stored values -> ddp[s*32+h*4+bx]; normalized in gemm_fin.
__global__ __launch_bounds__(256) void gemm_sme(
    const bfu* __restrict__ Xb, const bfu* __restrict__ Mb,
    bfu* __restrict__ Ecat, const float* __restrict__ cb,
    float* __restrict__ ddp) {
  __shared__ __align__(16) bfu S[32768];  // 2 x (At 128x64 + Bt 128x64) = 64KB
  const int tid = threadIdx.x;
  const int lane = tid & 63;
  const int wid = tid >> 6;
  const int l15 = lane & 15, l4 = lane >> 4;
  const int wm = wid >> 1, wn = wid & 1;

  // XCD swizzle: nwg=2048, chunk=256. Within a chunk h is SLOWEST: per h the
  // XCD touches A panels (1 MB, L2-resident across all h) + B_h (512 KB).
  const int bid = blockIdx.x;
  const int swz = ((bid & 7) << 8) + (bid >> 3);
  const int h  = (swz >> 5) & 7;
  const int by = ((swz >> 2) & 7) + (swz >> 8) * 8;  // 0..63
  const int bx = swz & 3;

  const int m0 = by * 128;
  const int n0l = bx * 128;       // col-block within head
  const bfu* Ag = Xb + (long long)m0 * 512;
  const bfu* Bg = Mb + (long long)h * 262144 + (long long)n0l * 512;

  f32x4 acc[4][4];
  const f32x4 zero = {0.f, 0.f, 0.f, 0.f};
#pragma unroll
  for (int r = 0; r < 4; ++r)
#pragma unroll
    for (int c = 0; c < 4; ++c) acc[r][c] = zero;

  const int lrow = lane >> 3;
  const int ldst = (lane & 7) * 8;
  const int lsrc = ldst ^ (lrow * 8);
  const int ksw = (l15 & 7) * 8;

  auto STAGE = [&](int kt, bfu* buf) {
    const bfu* Ak = Ag + kt * 64;
    const bfu* Bk = Bg + kt * 64;
#pragma unroll
    for (int j = 0; j < 4; ++j) {
      const int row = (wid * 4 + j) * 8 + lrow;
      stage16(Ak + (long long)row * 512 + lsrc, buf + row * 64 + ldst);
    }
#pragma unroll
    for (int j = 0; j < 4; ++j) {
      const int row = (wid * 4 + j) * 8 + lrow;
      stage16(Bk + (long long)row * 512 + lsrc, buf + 8192 + row * 64 + ldst);
    }
  };

  STAGE(0, S);
  asm volatile("s_waitcnt vmcnt(0)" ::: "memory");
  __builtin_amdgcn_s_barrier();

  for (int kt = 0; kt < 8; ++kt) {   // K = 512
    bfu* bufc = S + ((kt & 1) ? 16384 : 0);
    bfu* bufn = S + ((kt & 1) ? 0 : 16384);
    if (kt + 1 < 8) STAGE(kt + 1, bufn);
#pragma unroll
    for (int kk = 0; kk < 2; ++kk) {
      const int ko = (kk * 32 + l4 * 8) ^ ksw;
      bf16x8 af[4], bfr[4];
#pragma unroll
      for (int r = 0; r < 4; ++r)
        af[r] = *(const bf16x8*)(bufc + (wm * 64 + r * 16 + l15) * 64 + ko);
#pragma unroll
      for (int c = 0; c < 4; ++c)
        bfr[c] = *(const bf16x8*)(bufc + 8192 + (wn * 64 + c * 16 + l15) * 64 + ko);
#pragma unroll
      for (int r = 0; r < 4; ++r)
#pragma unroll
        for (int c = 0; c < 4; ++c)
          acc[r][c] = __builtin_amdgcn_mfma_f32_16x16x32_bf16(af[r], bfr[c], acc[r][c], 0, 0, 0);
    }
    asm volatile("s_waitcnt vmcnt(0)" ::: "memory");
    __builtin_amdgcn_s_barrier();
  }

  // ---- repack with exp fused (XOR-swizzled); no register-resident results ----
  const float scale = 0.044194173824159216f;  // 1/sqrt(512)
  float ch[4];
#pragma unroll
  for (int c = 0; c < 4; ++c)
    ch[c] = cb[h * 512 + n0l + wn * 64 + c * 16 + l15];
#pragma unroll
  for (int r = 0; r < 4; ++r)
#pragma unroll
    for (int c = 0; c < 4; ++c) {
      const int col = wn * 64 + c * 16 + l15;
#pragma unroll
      for (int v = 0; v < 4; ++v) {
        const int row = wm * 64 + r * 16 + (l4 << 2) + v;
        S[row * 128 + (col ^ (((row >> 2) & 3) << 4))] =
            f2b(__expf((acc[r][c][v] + ch[c]) * scale));
      }
    }
  __syncthreads();

  // ---- store + row-sum from the stored (bf16-rounded) values ----
#pragma unroll
  for (int i = 0; i < 8; ++i) {
    const int j = i * 256 + tid;
    const int row = j >> 4;            // 0..127
    const int colbase = (j & 15) * 8;  // 0..120
    const int sc = colbase ^ (((row >> 2) & 3) << 4);
    union { uint4 u; bfu us[8]; } pk;
    pk.u = *(const uint4*)(S + row * 128 + sc);
    *(uint4*)(Ecat + (long long)(m0 + row) * 4096 + h * 512 + n0l + colbase) = pk.u;
    float s = 0.f;
#pragma unroll
    for (int e = 0; e < 8; ++e) s += b2f(pk.us[e]);
#pragma unroll
    for (int off = 1; off < 16; off <<= 1) s += __shfl_xor(s, off, 64);
    if ((tid & 15) == 0)
      ddp[(long long)(m0 + row) * 32 + h * 4 + bx] = s;
  }
}

// invD2[h*8192 + s] = 1 / sum_bx ddp[s*32 + h*4 + bx]
__global__ __launch_bounds__(256) void inv_k(const float* __restrict__ ddp,
                                             float* __restrict__ invD2) {
  const int i = blockIdx.x * 256 + threadIdx.x;  // s*8+h, 65536 total
  f32x4 p = *(const f32x4*)(ddp + (long long)i * 4);
  const int s = i >> 3, h = i & 7;
  invD2[h * 8192 + s] = 1.0f / (p[0] + p[1] + p[2] + p[3]);
}

// ---------------------------------------------------------------------------
// Final GEMM with per-head normalization:
//   out[s][o] = bias[o] + sum_h (1/D[h][s]) * sum_a expE[s][h*512+a]*Ncat[o][h*512+a]
// 64x128 tile, 512 blocks (2/CU), PIPE=3 counted vmcnt, XCD swizzle.
__global__ __launch_bounds__(256) void gemm_fin(
    const bfu* __restrict__ A, const bfu* __restrict__ B, float* __restrict__ C,
    const float* __restrict__ bias, const float* __restrict__ invD2) {
  __shared__ __align__(16) bfu S[36864];  // 3 x 24KB
  const int tid = threadIdx.x;
  const int lane = tid & 63;
  const int wid = tid >> 6;
  const int l15 = lane & 15, l4 = lane >> 4;
  const int wm = wid >> 1, wn = wid & 1;

  const int bid = blockIdx.x;
  const int swz = ((bid & 7) << 6) + (bid >> 3);
  const int m0 = (swz >> 2) * 64;
  const int n0 = (swz & 3) * 128;
  const bfu* Ag = A + (long long)m0 * 4096;
  const bfu* Bg = B + (long long)n0 * 4096;

  // preload inverse denominators: rows m0+wm*32+{0,16}+l4*4+v, per head
  f32x4 inv0[8], inv1[8];
#pragma unroll
  for (int h = 0; h < 8; ++h) {
    const float* p = invD2 + h * 8192 + m0 + wm * 32 + (l4 << 2);
    inv0[h] = *(const f32x4*)p;
    inv1[h] = *(const f32x4*)(p + 16);
  }

  f32x4 macc[2][4], acc[2][4];
  const f32x4 zero = {0.f, 0.f, 0.f, 0.f};
#pragma unroll
  for (int r = 0; r < 2; ++r)
#pragma unroll
    for (int c = 0; c < 4; ++c) { macc[r][c] = zero; acc[r][c] = zero; }

  const int lrow = lane >> 3;
  const int ldst = (lane & 7) * 8;
  const int lsrc = ldst ^ (lrow * 8);
  const int ksw = (l15 & 7) * 8;

  auto STAGE = [&](int kt, bfu* buf) {  // 6 gload_lds per lane
    const bfu* Ak = Ag + kt * 64;
    const bfu* Bk = Bg + kt * 64;
#pragma unroll
    for (int j = 0; j < 2; ++j) {
      const int row = (wid * 2 + j) * 8 + lrow;
      stage16(Ak + (long long)row * 4096 + lsrc, buf + row * 64 + ldst);
    }
#pragma unroll
    for (int j = 0; j < 4; ++j) {
      const int row = (wid * 4 + j) * 8 + lrow;
      stage16(Bk + (long long)row * 4096 + lsrc, buf + 4096 + row * 64 + ldst);
    }
  };

  // drain preloads so staged-load counting below is exact
  asm volatile("s_waitcnt vmcnt(0)" ::: "memory");

  STAGE(0, S);
  STAGE(1, S + 12288);

  for (int kt = 0; kt < 64; ++kt) {   // K = 4096
    if (kt > 0) __builtin_amdgcn_s_barrier();
    if (kt + 2 < 64) STAGE(kt + 2, S + 12288 * ((kt + 2) % 3));
    const int rem = 63 - kt;
    if (rem >= 2)
      asm volatile("s_waitcnt vmcnt(12)" ::: "memory");
    else if (rem == 1)
      asm volatile("s_waitcnt vmcnt(6)" ::: "memory");
    else
      asm volatile("s_waitcnt vmcnt(0)" ::: "memory");
    __builtin_amdgcn_s_barrier();

    const bfu* bufc = S + 12288 * (kt % 3);
#pragma unroll
    for (int kk = 0; kk < 2; ++kk) {
      const int ko = (kk * 32 + l4 * 8) ^ ksw;
      bf16x8 af[2], bfr[4];
#pragma unroll
      for (int r = 0; r < 2; ++r)
        af[r] = *(const bf16x8*)(bufc + (wm * 32 + r * 16 + l15) * 64 + ko);
#pragma unroll
      for (int c = 0; c < 4; ++c)
        bfr[c] = *(const bf16x8*)(bufc + 4096 + (wn * 64 + c * 16 + l15) * 64 + ko);
#pragma unroll
      for (int r = 0; r < 2; ++r)
#pragma unroll
        for (int c = 0; c < 4; ++c)
          acc[r][c] = __builtin_amdgcn_mfma_f32_16x16x32_bf16(af[r], bfr[c], acc[r][c], 0, 0, 0);
    }

    if ((kt & 7) == 7) {  // head boundary: fold seg into master with 1/D
#pragma unroll
      for (int r = 0; r < 2; ++r) {
        const f32x4 iv = r ? inv1[0] : inv0[0];
#pragma unroll
        for (int c = 0; c < 4; ++c) {
#pragma unroll
          for (int v = 0; v < 4; ++v) macc[r][c][v] += acc[r][c][v] * iv[v];
          acc[r][c] = zero;
        }
      }
#pragma unroll
      for (int q = 0; q < 7; ++q) { inv0[q] = inv0[q + 1]; inv1[q] = inv1[q + 1]; }
    }
  }

  // f32 + bias store
#pragma unroll
  for (int r = 0; r < 2; ++r) {
#pragma unroll
    for (int c = 0; c < 4; ++c) {
      const int gr = m0 + wm * 32 + r * 16 + (l4 << 2);
      const int gc = n0 + wn * 64 + c * 16 + l15;
      const float bval = bias[gc];
#pragma unroll
      for (int v = 0; v < 4; ++v)
        C[(long long)(gr + v) * 512 + gc] = macc[r][c][v] + bval;
    }
  }
}

// ---------------- helpers ----------------
// fused: Xb (bf16 copy) + XTb (bf16 transpose) from one read of X.
__global__ void convT_x(const float* __restrict__ in, bfu* __restrict__ outN,
                        bfu* __restrict__ outT, int R, int C) {
  __shared__ bfu t[32][33];
  const int c0 = blockIdx.x * 32, r0 = blockIdx.y * 32;
  const int tx = threadIdx.x, ty = threadIdx.y;
  for (int i = ty; i < 32; i += 8) {
    bfu b = f2b(in[(long long)(r0 + i) * C + (c0 + tx)]);
    outN[(long long)(r0 + i) * C + (c0 + tx)] = b;
    t[i][tx] = b;
  }
  __syncthreads();
  for (int i = ty; i < 32; i += 8)
    outT[(long long)(c0 + i) * R + (r0 + tx)] = t[tx][i];
}

__global__ void transpose_k(const float* __restrict__ in, bfu* __restrict__ out,
                            int R, int C) {
  __shared__ bfu t[32][33];
  const long long boff = (long long)blockIdx.z * R * C;
  const int c0 = blockIdx.x * 32, r0 = blockIdx.y * 32;
  const int tx = threadIdx.x, ty = threadIdx.y;
  for (int i = ty; i < 32; i += 8)
    t[i][tx] = f2b(in[boff + (long long)(r0 + i) * C + (c0 + tx)]);
  __syncthreads();
  for (int i = ty; i < 32; i += 8)
    out[boff + (long long)(c0 + i) * R + (r0 + tx)] = t[tx][i];
}

// one pass: enc0 -> encb[0:16MB), enc1 -> encb[16MB:32MB) (contiguous stacked
// [1024][8192] bf16), Wc -> wcb.
__global__ __launch_bounds__(256) void conv_all(
    const float* __restrict__ e0, const float* __restrict__ e1,
    const float* __restrict__ wc, bfu* __restrict__ encb, bfu* __restrict__ wcb) {
  int i = blockIdx.x * 256 + threadIdx.x;  // < 2621440 float4 units
  float4 f;
  ushort4* d;
  if (i < 1048576) {
    f = ((const float4*)e0)[i];
    d = (ushort4*)encb + i;
  } else if (i < 2097152) {
    f = ((const float4*)e1)[i - 1048576];
    d = (ushort4*)encb + i;
  } else {
    f = ((const float4*)wc)[i - 2097152];
    d = (ushort4*)wcb + (i - 2097152);
  }
  ushort4 o;
  o.x = f2b(f.x); o.y = f2b(f.y); o.z = f2b(f.z); o.w = f2b(f.w);
  *d = o;
}

__global__ __launch_bounds__(256) void zero_out_k(float* __restrict__ p, int n) {
  int i = blockIdx.x * 256 + threadIdx.x;
  if (i < n) p[i] = 0.f;
}

// KVp[8][1024][512] -> rows 0..511 = K (write K32 f32 + Kb bf16),
// rows 512..1023 = V (write V32 f32, transposed to VTb separately).
__global__ __launch_bounds__(256) void reduce_kv2(
    const float* __restrict__ KVp, float* __restrict__ K32,
    float* __restrict__ V32, bfu* __restrict__ Kb) {
  const int i = blockIdx.x * 256 + threadIdx.x;  // < 524288
  float s = 0.f;
#pragma unroll
  for (int z = 0; z < 8; ++z) s += KVp[(long long)z * 524288 + i];
  if (i < 262144) {
    K32[i] = s;
    Kb[i] = f2b(s);
  } else {
    V32[i - 262144] = s;
  }
}

__global__ __launch_bounds__(256) void cvec_k(const float* __restrict__ K32,
                                              const float* __restrict__ bq,
                                              float* __restrict__ cb) {
  const int lane = threadIdx.x & 63;
  const int w = blockIdx.x * 4 + (threadIdx.x >> 6);
  const int h = w >> 9, a = w & 511;
  float s = 0.f;
#pragma unroll
  for (int i = 0; i < 8; ++i) {
    int q = i * 64 + lane;
    s += K32[a * 512 + q] * bq[h * 512 + q];
  }
#pragma unroll
  for (int off = 32; off; off >>= 1) s += __shfl_xor(s, off, 64);
  if (lane == 0) cb[w] = s;
}

extern "C" void kernel_launch(void* const* d_in, const int* in_sizes, int n_in,
                              void* d_out, int out_size, void* d_ws, size_t ws_size,
                              hipStream_t stream) {
  (void)in_sizes; (void)n_in;
  const float* X    = (const float*)d_in[0];  // [8192,512]
  const float* enc0 = (const float*)d_in[1];  // [512,8192]
  const float* enc1 = (const float*)d_in[2];  // [512,8192]
  const float* Wq   = (const float*)d_in[3];  // [8,512,512]
  const float* bq   = (const float*)d_in[4];  // [8,512]
  const float* Wc   = (const float*)d_in[5];  // [512,4096]
  const float* bc   = (const float*)d_in[6];  // [512]
  float* out = (float*)d_out;                 // [8192,512] f32

  const size_t NEED = 83902464;  // 80.02 MB (unchanged)
  if (ws_size < NEED) {
    zero_out_k<<<dim3((out_size + 255) / 256), 256, 0, stream>>>(out, out_size);
    return;
  }
  char* w = (char*)d_ws;
  // Ecat (64 MB) overlays ALL transients below 67108864.
  bfu*   Ecat  = (bfu*)(w + 0);           // [8192][4096] 64 MB
  bfu*   XTb   = (bfu*)(w + 0);           // [512][8192]   8 MB (dead after KV)
  bfu*   encb  = (bfu*)(w + 8388608);     // [1024][8192] 16 MB stacked enc0|enc1
  float* KVp32 = (float*)(w + 25165824);  // [8][1024][512] 16 MB (dead after reduce)
  bfu*   WqTb  = (bfu*)(w + 58720256);    // [8][512][512]  4 MB (dead after gemm_mn)
  bfu*   Wcb   = (bfu*)(w + 62914560);    // [512][4096]    4 MB (dead after gemm_mn)
  // reuse the dead XTb slab (written after the KV gemm):
  float* K32   = (float*)(w + 0);         // [512][512]    1 MB
  float* V32   = (float*)(w + 1048576);   // [512][512]    1 MB
  bfu*   Kb    = (bfu*)(w + 2097152);     // [512][512]  0.5 MB
  bfu*   VTb   = (bfu*)(w + 2621440);     // [512][512]  0.5 MB
  // persistent tail:
  bfu*   Xb    = (bfu*)(w + 67108864);    // [8192][512]   8 MB
  bfu*   Mb    = (bfu*)(w + 75497472);    // [8][512][512] 4 MB (dead after sme)
  float* invD2 = (float*)(w + 75497472);  // [8][8192] 256 KB, overlays dead Mb
  bfu*   Ncat  = (bfu*)(w + 79691776);    // [512][4096]   4 MB
  float* cb    = (float*)(w + 83886080);  // [8][512]     16 KB
  // ddp scratch lives in d_out (dead until gemm_fin; inv_k runs between):
  float* ddp   = out;                     // [8192][8][4]  1 MB

  // all bf16 input conversions in one pass
  conv_all<<<dim3(10240), 256, 0, stream>>>(enc0, enc1, Wc, encb, Wcb);

  dim3 tb(32, 8, 1);
  convT_x<<<dim3(16, 256, 1), tb, 0, stream>>>(X, Xb, XTb, 8192, 512);
  transpose_k<<<dim3(16, 16, 8), tb, 0, stream>>>(Wq, WqTb, 512, 512);

  // [K;V] = [enc0;enc1] @ X: ONE stacked gemm (M=1024), split-K=8 -> 512 blocks
  gemm64p<3><<<dim3(4, 16, 8), 256, 0, stream>>>(encb, XTb, KVp32,
      8192, 8192, 512, 0, 0, 524288, 1024, 1);
  reduce_kv2<<<dim3(2048), 256, 0, stream>>>(KVp32, K32, V32, Kb);
  transpose_k<<<dim3(16, 16, 1), tb, 0, stream>>>(V32, VTb, 512, 512);
  cvec_k<<<dim3(1024), 256, 0, stream>>>(K32, bq, cb);

  // merged M/N gemms (z<8: M_h = Kb@WqTb_h^T; z>=8: N_h = Wcb_h@VTb^T)
  gemm_mn<<<dim3(4, 8, 16), 256, 0, stream>>>(Kb, WqTb, Mb, Wcb, VTb, Ncat);

  // fused logits+exp -> Ecat (unnormalized) + row-sum partials -> ddp
  gemm_sme<<<dim3(2048), 256, 0, stream>>>(Xb, Mb, Ecat, cb, ddp);
  inv_k<<<dim3(256), 256, 0, stream>>>(ddp, invD2);

  // out = bc + sum_h (Ecat_h @ Ncat_h^T) / D_h
  gemm_fin<<<dim3(512), 256, 0, stream>>>(Ecat, Ncat, out, bc, invD2);
}

// Round 9
// 252.405 us; speedup vs baseline: 1.2224x; 1.0521x over previous
//
#include <hip/hip_runtime.h>
#include <stdint.h>

typedef unsigned short bfu;
typedef __attribute__((ext_vector_type(8))) short bf16x8;   // MFMA A/B frag
typedef __attribute__((ext_vector_type(4))) float f32x4;    // MFMA C/D frag

__device__ __forceinline__ bfu f2b(float f) {
  unsigned int i = __builtin_bit_cast(unsigned int, f);
  i += 0x7FFFu + ((i >> 16) & 1u);  // round-to-nearest-even
  return (bfu)(i >> 16);
}
__device__ __forceinline__ float b2f(bfu b) {
  return __builtin_bit_cast(float, ((unsigned int)b) << 16);
}

// async global->LDS, 16B per lane. LDS dest must be wave-uniform base + lane*16.
__device__ __forceinline__ void stage16(const bfu* g, bfu* l) {
  __builtin_amdgcn_global_load_lds(
      (const __attribute__((address_space(1))) void*)g,
      (__attribute__((address_space(3))) void*)l, 16, 0, 0);
}

// ---------------------------------------------------------------------------
// KV gemm: KVp[z][1024][512] = [enc0;enc1][1024, z*1024:(z+1)*1024] @ XTb^T.
// 64x128 tile, PIPE=3 counted vmcnt (fin-proven loop), 512 blocks = 2/CU.
// f32 split-K partial store.
__global__ __launch_bounds__(256) void gemm_kv(
    const bfu* __restrict__ A, const bfu* __restrict__ B, float* __restrict__ C) {
  __shared__ __align__(16) bfu S[36864];  // 3 x (At 64x64 + Bt 128x64) = 72KB
  const int tid = threadIdx.x;
  const int lane = tid & 63;
  const int wid = tid >> 6;
  const int l15 = lane & 15, l4 = lane >> 4;
  const int wm = wid >> 1, wn = wid & 1;

  const int k0 = blockIdx.z * 1024;
  const long long cOff = (long long)blockIdx.z * 524288;
  const int m0 = blockIdx.y * 64;    // 0..960
  const int n0 = blockIdx.x * 128;   // 0..384
  const bfu* Ag = A + (long long)m0 * 8192 + k0;
  const bfu* Bg = B + (long long)n0 * 8192 + k0;

  f32x4 acc[2][4];
  const f32x4 zero = {0.f, 0.f, 0.f, 0.f};
#pragma unroll
  for (int r = 0; r < 2; ++r)
#pragma unroll
    for (int c = 0; c < 4; ++c) acc[r][c] = zero;

  const int lrow = lane >> 3;
  const int ldst = (lane & 7) * 8;
  const int lsrc = ldst ^ (lrow * 8);
  const int ksw = (l15 & 7) * 8;

  auto STAGE = [&](int kt, bfu* buf) {  // 6 gload_lds per lane
    const bfu* Ak = Ag + kt * 64;
    const bfu* Bk = Bg + kt * 64;
#pragma unroll
    for (int j = 0; j < 2; ++j) {
      const int row = (wid * 2 + j) * 8 + lrow;
      stage16(Ak + (long long)row * 8192 + lsrc, buf + row * 64 + ldst);
    }
#pragma unroll
    for (int j = 0; j < 4; ++j) {
      const int row = (wid * 4 + j) * 8 + lrow;
      stage16(Bk + (long long)row * 8192 + lsrc, buf + 4096 + row * 64 + ldst);
    }
  };

  STAGE(0, S);
  STAGE(1, S + 12288);

  for (int kt = 0; kt < 16; ++kt) {   // Klen = 1024
    if (kt > 0) __builtin_amdgcn_s_barrier();
    if (kt + 2 < 16) STAGE(kt + 2, S + 12288 * ((kt + 2) % 3));
    const int rem = 15 - kt;
    if (rem >= 2)
      asm volatile("s_waitcnt vmcnt(12)" ::: "memory");
    else if (rem == 1)
      asm volatile("s_waitcnt vmcnt(6)" ::: "memory");
    else
      asm volatile("s_waitcnt vmcnt(0)" ::: "memory");
    __builtin_amdgcn_s_barrier();

    const bfu* bufc = S + 12288 * (kt % 3);
#pragma unroll
    for (int kk = 0; kk < 2; ++kk) {
      const int ko = (kk * 32 + l4 * 8) ^ ksw;
      bf16x8 af[2], bfr[4];
#pragma unroll
      for (int r = 0; r < 2; ++r)
        af[r] = *(const bf16x8*)(bufc + (wm * 32 + r * 16 + l15) * 64 + ko);
#pragma unroll
      for (int c = 0; c < 4; ++c)
        bfr[c] = *(const bf16x8*)(bufc + 4096 + (wn * 64 + c * 16 + l15) * 64 + ko);
#pragma unroll
      for (int r = 0; r < 2; ++r)
#pragma unroll
        for (int c = 0; c < 4; ++c)
          acc[r][c] = __builtin_amdgcn_mfma_f32_16x16x32_bf16(af[r], bfr[c], acc[r][c], 0, 0, 0);
    }
  }

  // f32 partial store (no LDS reuse; no trailing barrier needed)
#pragma unroll
  for (int r = 0; r < 2; ++r) {
#pragma unroll
    for (int c = 0; c < 4; ++c) {
      const int gr = m0 + wm * 32 + r * 16 + (l4 << 2);
      const int gc = n0 + wn * 64 + c * 16 + l15;
#pragma unroll
      for (int v = 0; v < 4; ++v)
        C[cOff + (long long)(gr + v) * 512 + gc] = acc[r][c][v];
    }
  }
}

// ---------------------------------------------------------------------------
// Merged M/N GEMM (both 512x512x512 per head; 512 blocks = 2/CU), PIPE=3
// counted vmcnt:
//   z<8 : M_h = Kb @ WqTb_h^T  -> Mb[h]
//   z>=8: N_h = Wcb[:,h*512:] @ VTb^T -> Ncat[:,h*512:]
// Repack region S[0..8192) = buf0; last two tiles live in buf1/buf2 -> the
// post-loop repack never races a slow wave's tile-7 reads.
__global__ __launch_bounds__(256) void gemm_mn(
    const bfu* __restrict__ Kb, const bfu* __restrict__ WqTb, bfu* __restrict__ Mbp,
    const bfu* __restrict__ Wcb, const bfu* __restrict__ VTb, bfu* __restrict__ Ncat) {
  __shared__ __align__(16) bfu S[36864];  // 3 x 24KB
  const int tid = threadIdx.x;
  const int lane = tid & 63;
  const int wid = tid >> 6;
  const int l15 = lane & 15, l4 = lane >> 4;
  const int wm = wid >> 1, wn = wid & 1;

  const int z = blockIdx.z;
  const bfu* A; const bfu* B; bfu* Cb; int lda, ldb, ldc; long long cOff;
  if (z < 8) {
    A = Kb;                               lda = 512;
    B = WqTb + (long long)z * 262144;     ldb = 512;
    Cb = Mbp;  ldc = 512;  cOff = (long long)z * 262144;
  } else {
    A = Wcb + (long long)(z - 8) * 512;   lda = 4096;
    B = VTb;                              ldb = 512;
    Cb = Ncat; ldc = 4096; cOff = (long long)(z - 8) * 512;
  }
  const int m0 = blockIdx.y * 64;
  const int n0 = blockIdx.x * 128;
  const bfu* Ag = A + (long long)m0 * lda;
  const bfu* Bg = B + (long long)n0 * ldb;

  f32x4 acc[2][4];
  const f32x4 zero = {0.f, 0.f, 0.f, 0.f};
#pragma unroll
  for (int r = 0; r < 2; ++r)
#pragma unroll
    for (int c = 0; c < 4; ++c) acc[r][c] = zero;

  const int lrow = lane >> 3;
  const int ldst = (lane & 7) * 8;
  const int lsrc = ldst ^ (lrow * 8);
  const int ksw = (l15 & 7) * 8;

  auto STAGE = [&](int kt, bfu* buf) {
    const bfu* Ak = Ag + kt * 64;
    const bfu* Bk = Bg + kt * 64;
#pragma unroll
    for (int j = 0; j < 2; ++j) {
      const int row = (wid * 2 + j) * 8 + lrow;
      stage16(Ak + (long long)row * lda + lsrc, buf + row * 64 + ldst);
    }
#pragma unroll
    for (int j = 0; j < 4; ++j) {
      const int row = (wid * 4 + j) * 8 + lrow;
      stage16(Bk + (long long)row * ldb + lsrc, buf + 4096 + row * 64 + ldst);
    }
  };

  STAGE(0, S);
  STAGE(1, S + 12288);

  for (int kt = 0; kt < 8; ++kt) {   // K = 512
    if (kt > 0) __builtin_amdgcn_s_barrier();
    if (kt + 2 < 8) STAGE(kt + 2, S + 12288 * ((kt + 2) % 3));
    const int rem = 7 - kt;
    if (rem >= 2)
      asm volatile("s_waitcnt vmcnt(12)" ::: "memory");
    else if (rem == 1)
      asm volatile("s_waitcnt vmcnt(6)" ::: "memory");
    else
      asm volatile("s_waitcnt vmcnt(0)" ::: "memory");
    __builtin_amdgcn_s_barrier();

    const bfu* bufc = S + 12288 * (kt % 3);
#pragma unroll
    for (int kk = 0; kk < 2; ++kk) {
      const int ko = (kk * 32 + l4 * 8) ^ ksw;
      bf16x8 af[2], bfr[4];
#pragma unroll
      for (int r = 0; r < 2; ++r)
        af[r] = *(const bf16x8*)(bufc + (wm * 32 + r * 16 + l15) * 64 + ko);
#pragma unroll
      for (int c = 0; c < 4; ++c)
        bfr[c] = *(const bf16x8*)(bufc + 4096 + (wn * 64 + c * 16 + l15) * 64 + ko);
#pragma unroll
      for (int r = 0; r < 2; ++r)
#pragma unroll
        for (int c = 0; c < 4; ++c)
          acc[r][c] = __builtin_amdgcn_mfma_f32_16x16x32_bf16(af[r], bfr[c], acc[r][c], 0, 0, 0);
    }
  }

  // bf16 repack epilogue (S[0..8192) = buf0 region; disjoint from buf1/buf2)
#pragma unroll
  for (int r = 0; r < 2; ++r) {
#pragma unroll
    for (int c = 0; c < 4; ++c) {
      const int col = wn * 64 + c * 16 + l15;
#pragma unroll
      for (int v = 0; v < 4; ++v) {
        const int row = wm * 32 + r * 16 + (l4 << 2) + v;
        S[row * 128 + (col ^ (((row >> 2) & 3) << 4))] = f2b(acc[r][c][v]);
      }
    }
  }
  __syncthreads();
#pragma unroll
  for (int i = 0; i < 4; ++i) {
    const int j = i * 256 + tid;
    const int row = j >> 4;
    const int colbase = (j & 15) * 8;
    const int sc = colbase ^ (((row >> 2) & 3) << 4);
    uint4 val = *(const uint4*)(S + row * 128 + sc);
    *(uint4*)(Cb + cOff + (long long)(m0 + row) * ldc + n0 + colbase) = val;
  }
}

// ---------------------------------------------------------------------------
// Fused logits+exp GEMM (proven round-7 structure; h-major XCD decode):
//   Ecat[s][h*512+a] = bf16(exp((X[s,:]@M_h[a,:]^T + cb[h,a]) / sqrt(512)))
// UNNORMALIZED (no max-sub: logits ~N(0,1.2)). Row-sum partials from the
// bf16-rounded stored values -> ddp[s*32+h*4+bx]; normalized in gemm_fin.
__global__ __launch_bounds__(256) void gemm_sme(
    const bfu* __restrict__ Xb, const bfu* __restrict__ Mb,
    bfu* __restrict__ Ecat, const float* __restrict__ cb,
    float* __restrict__ ddp) {
  __shared__ __align__(16) bfu S[32768];  // 2 x (At 128x64 + Bt 128x64) = 64KB
  const int tid = threadIdx.x;
  const int lane = tid & 63;
  const int wid = tid >> 6;
  const int l15 = lane & 15, l4 = lane >> 4;
  const int wm = wid >> 1, wn = wid & 1;

  // XCD swizzle: nwg=2048, chunk=256. Within a chunk h is SLOWEST: per h the
  // XCD touches A panels (1 MB, L2-resident across all h) + B_h (512 KB).
  const int bid = blockIdx.x;
  const int swz = ((bid & 7) << 8) + (bid >> 3);
  const int h  = (swz >> 5) & 7;
  const int by = ((swz >> 2) & 7) + (swz >> 8) * 8;  // 0..63
  const int bx = swz & 3;

  const int m0 = by * 128;
  const int n0l = bx * 128;       // col-block within head
  const bfu* Ag = Xb + (long long)m0 * 512;
  const bfu* Bg = Mb + (long long)h * 262144 + (long long)n0l * 512;

  f32x4 acc[4][4];
  const f32x4 zero = {0.f, 0.f, 0.f, 0.f};
#pragma unroll
  for (int r = 0; r < 4; ++r)
#pragma unroll
    for (int c = 0; c < 4; ++c) acc[r][c] = zero;

  const int lrow = lane >> 3;
  const int ldst = (lane & 7) * 8;
  const int lsrc = ldst ^ (lrow * 8);
  const int ksw = (l15 & 7) * 8;

  auto STAGE = [&](int kt, bfu* buf) {
    const bfu* Ak = Ag + kt * 64;
    const bfu* Bk = Bg + kt * 64;
#pragma unroll
    for (int j = 0; j < 4; ++j) {
      const int row = (wid * 4 + j) * 8 + lrow;
      stage16(Ak + (long long)row * 512 + lsrc, buf + row * 64 + ldst);
    }
#pragma unroll
    for (int j = 0; j < 4; ++j) {
      const int row = (wid * 4 + j) * 8 + lrow;
      stage16(Bk + (long long)row * 512 + lsrc, buf + 8192 + row * 64 + ldst);
    }
  };

  STAGE(0, S);
  asm volatile("s_waitcnt vmcnt(0)" ::: "memory");
  __builtin_amdgcn_s_barrier();

  for (int kt = 0; kt < 8; ++kt) {   // K = 512
    bfu* bufc = S + ((kt & 1) ? 16384 : 0);
    bfu* bufn = S + ((kt & 1) ? 0 : 16384);
    if (kt + 1 < 8) STAGE(kt + 1, bufn);
#pragma unroll
    for (int kk = 0; kk < 2; ++kk) {
      const int ko = (kk * 32 + l4 * 8) ^ ksw;
      bf16x8 af[4], bfr[4];
#pragma unroll
      for (int r = 0; r < 4; ++r)
        af[r] = *(const bf16x8*)(bufc + (wm * 64 + r * 16 + l15) * 64 + ko);
#pragma unroll
      for (int c = 0; c < 4; ++c)
        bfr[c] = *(const bf16x8*)(bufc + 8192 + (wn * 64 + c * 16 + l15) * 64 + ko);
#pragma unroll
      for (int r = 0; r < 4; ++r)
#pragma unroll
        for (int c = 0; c < 4; ++c)
          acc[r][c] = __builtin_amdgcn_mfma_f32_16x16x32_bf16(af[r], bfr[c], acc[r][c], 0, 0, 0);
    }
    asm volatile("s_waitcnt vmcnt(0)" ::: "memory");
    __builtin_amdgcn_s_barrier();
  }

  // ---- repack with exp fused (XOR-swizzled); no register-resident results ----
  const float scale = 0.044194173824159216f;  // 1/sqrt(512)
  float ch[4];
#pragma unroll
  for (int c = 0; c < 4; ++c)
    ch[c] = cb[h * 512 + n0l + wn * 64 + c * 16 + l15];
#pragma unroll
  for (int r = 0; r < 4; ++r)
#pragma unroll
    for (int c = 0; c < 4; ++c) {
      const int col = wn * 64 + c * 16 + l15;
#pragma unroll
      for (int v = 0; v < 4; ++v) {
        const int row = wm * 64 + r * 16 + (l4 << 2) + v;
        S[row * 128 + (col ^ (((row >> 2) & 3) << 4))] =
            f2b(__expf((acc[r][c][v] + ch[c]) * scale));
      }
    }
  __syncthreads();

  // ---- store + row-sum from the stored (bf16-rounded) values ----
#pragma unroll
  for (int i = 0; i < 8; ++i) {
    const int j = i * 256 + tid;
    const int row = j >> 4;            // 0..127
    const int colbase = (j & 15) * 8;  // 0..120
    const int sc = colbase ^ (((row >> 2) & 3) << 4);
    union { uint4 u; bfu us[8]; } pk;
    pk.u = *(const uint4*)(S + row * 128 + sc);
    *(uint4*)(Ecat + (long long)(m0 + row) * 4096 + h * 512 + n0l + colbase) = pk.u;
    float s = 0.f;
#pragma unroll
    for (int e = 0; e < 8; ++e) s += b2f(pk.us[e]);
#pragma unroll
    for (int off = 1; off < 16; off <<= 1) s += __shfl_xor(s, off, 64);
    if ((tid & 15) == 0)
      ddp[(long long)(m0 + row) * 32 + h * 4 + bx] = s;
  }
}

// invD2[h*8192 + s] = 1 / sum_bx ddp[s*32 + h*4 + bx]
__global__ __launch_bounds__(256) void inv_k(const float* __restrict__ ddp,
                                             float* __restrict__ invD2) {
  const int i = blockIdx.x * 256 + threadIdx.x;  // s*8+h, 65536 total
  f32x4 p = *(const f32x4*)(ddp + (long long)i * 4);
  const int s = i >> 3, h = i & 7;
  invD2[h * 8192 + s] = 1.0f / (p[0] + p[1] + p[2] + p[3]);
}

// ---------------------------------------------------------------------------
// Final GEMM with per-head normalization:
//   out[s][o] = bias[o] + sum_h (1/D[h][s]) * sum_a expE[s][h*512+a]*Ncat[o][h*512+a]
// 64x128 tile, 512 blocks (2/CU), PIPE=3 counted vmcnt, XCD swizzle.
__global__ __launch_bounds__(256) void gemm_fin(
    const bfu* __restrict__ A, const bfu* __restrict__ B, float* __restrict__ C,
    const float* __restrict__ bias, const float* __restrict__ invD2) {
  __shared__ __align__(16) bfu S[36864];  // 3 x 24KB
  const int tid = threadIdx.x;
  const int lane = tid & 63;
  const int wid = tid >> 6;
  const int l15 = lane & 15, l4 = lane >> 4;
  const int wm = wid >> 1, wn = wid & 1;

  const int bid = blockIdx.x;
  const int swz = ((bid & 7) << 6) + (bid >> 3);
  const int m0 = (swz >> 2) * 64;
  const int n0 = (swz & 3) * 128;
  const bfu* Ag = A + (long long)m0 * 4096;
  const bfu* Bg = B + (long long)n0 * 4096;

  // preload inverse denominators: rows m0+wm*32+{0,16}+l4*4+v, per head
  f32x4 inv0[8], inv1[8];
#pragma unroll
  for (int h = 0; h < 8; ++h) {
    const float* p = invD2 + h * 8192 + m0 + wm * 32 + (l4 << 2);
    inv0[h] = *(const f32x4*)p;
    inv1[h] = *(const f32x4*)(p + 16);
  }

  f32x4 macc[2][4], acc[2][4];
  const f32x4 zero = {0.f, 0.f, 0.f, 0.f};
#pragma unroll
  for (int r = 0; r < 2; ++r)
#pragma unroll
    for (int c = 0; c < 4; ++c) { macc[r][c] = zero; acc[r][c] = zero; }

  const int lrow = lane >> 3;
  const int ldst = (lane & 7) * 8;
  const int lsrc = ldst ^ (lrow * 8);
  const int ksw = (l15 & 7) * 8;

  auto STAGE = [&](int kt, bfu* buf) {  // 6 gload_lds per lane
    const bfu* Ak = Ag + kt * 64;
    const bfu* Bk = Bg + kt * 64;
#pragma unroll
    for (int j = 0; j < 2; ++j) {
      const int row = (wid * 2 + j) * 8 + lrow;
      stage16(Ak + (long long)row * 4096 + lsrc, buf + row * 64 + ldst);
    }
#pragma unroll
    for (int j = 0; j < 4; ++j) {
      const int row = (wid * 4 + j) * 8 + lrow;
      stage16(Bk + (long long)row * 4096 + lsrc, buf + 4096 + row * 64 + ldst);
    }
  };

  // drain preloads so staged-load counting below is exact
  asm volatile("s_waitcnt vmcnt(0)" ::: "memory");

  STAGE(0, S);
  STAGE(1, S + 12288);

  for (int kt = 0; kt < 64; ++kt) {   // K = 4096
    if (kt > 0) __builtin_amdgcn_s_barrier();
    if (kt + 2 < 64) STAGE(kt + 2, S + 12288 * ((kt + 2) % 3));
    const int rem = 63 - kt;
    if (rem >= 2)
      asm volatile("s_waitcnt vmcnt(12)" ::: "memory");
    else if (rem == 1)
      asm volatile("s_waitcnt vmcnt(6)" ::: "memory");
    else
      asm volatile("s_waitcnt vmcnt(0)" ::: "memory");
    __builtin_amdgcn_s_barrier();

    const bfu* bufc = S + 12288 * (kt % 3);
#pragma unroll
    for (int kk = 0; kk < 2; ++kk) {
      const int ko = (kk * 32 + l4 * 8) ^ ksw;
      bf16x8 af[2], bfr[4];
#pragma unroll
      for (int r = 0; r < 2; ++r)
        af[r] = *(const bf16x8*)(bufc + (wm * 32 + r * 16 + l15) * 64 + ko);
#pragma unroll
      for (int c = 0; c < 4; ++c)
        bfr[c] = *(const bf16x8*)(bufc + 4096 + (wn * 64 + c * 16 + l15) * 64 + ko);
#pragma unroll
      for (int r = 0; r < 2; ++r)
#pragma unroll
        for (int c = 0; c < 4; ++c)
          acc[r][c] = __builtin_amdgcn_mfma_f32_16x16x32_bf16(af[r], bfr[c], acc[r][c], 0, 0, 0);
    }

    if ((kt & 7) == 7) {  // head boundary: fold seg into master with 1/D
#pragma unroll
      for (int r = 0; r < 2; ++r) {
        const f32x4 iv = r ? inv1[0] : inv0[0];
#pragma unroll
        for (int c = 0; c < 4; ++c) {
#pragma unroll
          for (int v = 0; v < 4; ++v) macc[r][c][v] += acc[r][c][v] * iv[v];
          acc[r][c] = zero;
        }
      }
#pragma unroll
      for (int q = 0; q < 7; ++q) { inv0[q] = inv0[q + 1]; inv1[q] = inv1[q + 1]; }
    }
  }

  // f32 + bias store
#pragma unroll
  for (int r = 0; r < 2; ++r) {
#pragma unroll
    for (int c = 0; c < 4; ++c) {
      const int gr = m0 + wm * 32 + r * 16 + (l4 << 2);
      const int gc = n0 + wn * 64 + c * 16 + l15;
      const float bval = bias[gc];
#pragma unroll
      for (int v = 0; v < 4; ++v)
        C[(long long)(gr + v) * 512 + gc] = macc[r][c][v] + bval;
    }
  }
}

// ---------------- helpers ----------------
// fused: Xb (bf16 copy) + XTb (bf16 transpose) from one read of X.
__global__ void convT_x(const float* __restrict__ in, bfu* __restrict__ outN,
                        bfu* __restrict__ outT, int R, int C) {
  __shared__ bfu t[32][33];
  const int c0 = blockIdx.x * 32, r0 = blockIdx.y * 32;
  const int tx = threadIdx.x, ty = threadIdx.y;
  for (int i = ty; i < 32; i += 8) {
    bfu b = f2b(in[(long long)(r0 + i) * C + (c0 + tx)]);
    outN[(long long)(r0 + i) * C + (c0 + tx)] = b;
    t[i][tx] = b;
  }
  __syncthreads();
  for (int i = ty; i < 32; i += 8)
    outT[(long long)(c0 + i) * R + (r0 + tx)] = t[tx][i];
}

// merged transposes (all 512x512): z<8 -> Wq slice z; z==8 -> V32.
__global__ void transpose_wqv(const float* __restrict__ Wq, bfu* __restrict__ WqTb,
                              const float* __restrict__ V32, bfu* __restrict__ VTb) {
  __shared__ bfu t[32][33];
  const int z = blockIdx.z;
  const float* in;
  bfu* out;
  if (z < 8) {
    in = Wq + (long long)z * 262144;
    out = WqTb + (long long)z * 262144;
  } else {
    in = V32;
    out = VTb;
  }
  const int c0 = blockIdx.x * 32, r0 = blockIdx.y * 32;
  const int tx = threadIdx.x, ty = threadIdx.y;
  for (int i = ty; i < 32; i += 8)
    t[i][tx] = f2b(in[(long long)(r0 + i) * 512 + (c0 + tx)]);
  __syncthreads();
  for (int i = ty; i < 32; i += 8)
    out[(long long)(c0 + i) * 512 + (r0 + tx)] = t[tx][i];
}

// one pass: enc0 -> encb[0:16MB), enc1 -> encb[16MB:32MB) (contiguous stacked
// [1024][8192] bf16), Wc -> wcb.
__global__ __launch_bounds__(256) void conv_all(
    const float* __restrict__ e0, const float* __restrict__ e1,
    const float* __restrict__ wc, bfu* __restrict__ encb, bfu* __restrict__ wcb) {
  int i = blockIdx.x * 256 + threadIdx.x;  // < 2621440 float4 units
  float4 f;
  ushort4* d;
  if (i < 1048576) {
    f = ((const float4*)e0)[i];
    d = (ushort4*)encb + i;
  } else if (i < 2097152) {
    f = ((const float4*)e1)[i - 1048576];
    d = (ushort4*)encb + i;
  } else {
    f = ((const float4*)wc)[i - 2097152];
    d = (ushort4*)wcb + (i - 2097152);
  }
  ushort4 o;
  o.x = f2b(f.x); o.y = f2b(f.y); o.z = f2b(f.z); o.w = f2b(f.w);
  *d = o;
}

__global__ __launch_bounds__(256) void zero_out_k(float* __restrict__ p, int n) {
  int i = blockIdx.x * 256 + threadIdx.x;
  if (i < n) p[i] = 0.f;
}

// KVp[8][1024][512] -> rows 0..511 = K (write K32 f32 + Kb bf16),
// rows 512..1023 = V (write V32 f32; transposed to VTb by transpose_wqv).
__global__ __launch_bounds__(256) void reduce_kv2(
    const float* __restrict__ KVp, float* __restrict__ K32,
    float* __restrict__ V32, bfu* __restrict__ Kb) {
  const int i = blockIdx.x * 256 + threadIdx.x;  // < 524288
  float s = 0.f;
#pragma unroll
  for (int z = 0; z < 8; ++z) s += KVp[(long long)z * 524288 + i];
  if (i < 262144) {
    K32[i] = s;
    Kb[i] = f2b(s);
  } else {
    V32[i - 262144] = s;
  }
}

__global__ __launch_bounds__(256) void cvec_k(const float* __restrict__ K32,
                                              const float* __restrict__ bq,
                                              float* __restrict__ cb) {
  const int lane = threadIdx.x & 63;
  const int w = blockIdx.x * 4 + (threadIdx.x >> 6);
  const int h = w >> 9, a = w & 511;
  float s = 0.f;
#pragma unroll
  for (int i = 0; i < 8; ++i) {
    int q = i * 64 + lane;
    s += K32[a * 512 + q] * bq[h * 512 + q];
  }
#pragma unroll
  for (int off = 32; off; off >>= 1) s += __shfl_xor(s, off, 64);
  if (lane == 0) cb[w] = s;
}

extern "C" void kernel_launch(void* const* d_in, const int* in_sizes, int n_in,
                              void* d_out, int out_size, void* d_ws, size_t ws_size,
                              hipStream_t stream) {
  (void)in_sizes; (void)n_in;
  const float* X    = (const float*)d_in[0];  // [8192,512]
  const float* enc0 = (const float*)d_in[1];  // [512,8192]
  const float* enc1 = (const float*)d_in[2];  // [512,8192]
  const float* Wq   = (const float*)d_in[3];  // [8,512,512]
  const float* bq   = (const float*)d_in[4];  // [8,512]
  const float* Wc   = (const float*)d_in[5];  // [512,4096]
  const float* bc   = (const float*)d_in[6];  // [512]
  float* out = (float*)d_out;                 // [8192,512] f32

  const size_t NEED = 83902464;  // 80.02 MB (unchanged)
  if (ws_size < NEED) {
    zero_out_k<<<dim3((out_size + 255) / 256), 256, 0, stream>>>(out, out_size);
    return;
  }
  char* w = (char*)d_ws;
  // Ecat (64 MB) overlays ALL transients below 67108864.
  bfu*   Ecat  = (bfu*)(w + 0);           // [8192][4096] 64 MB
  bfu*   XTb   = (bfu*)(w + 0);           // [512][8192]   8 MB (dead after KV)
  bfu*   encb  = (bfu*)(w + 8388608);     // [1024][8192] 16 MB stacked enc0|enc1
  float* KVp32 = (float*)(w + 25165824);  // [8][1024][512] 16 MB (dead after reduce)
  bfu*   WqTb  = (bfu*)(w + 58720256);    // [8][512][512]  4 MB (dead after gemm_mn)
  bfu*   Wcb   = (bfu*)(w + 62914560);    // [512][4096]    4 MB (dead after gemm_mn)
  // reuse the dead XTb slab (written after the KV gemm):
  float* K32   = (float*)(w + 0);         // [512][512]    1 MB
  float* V32   = (float*)(w + 1048576);   // [512][512]    1 MB
  bfu*   Kb    = (bfu*)(w + 2097152);     // [512][512]  0.5 MB
  bfu*   VTb   = (bfu*)(w + 2621440);     // [512][512]  0.5 MB
  // persistent tail:
  bfu*   Xb    = (bfu*)(w + 67108864);    // [8192][512]   8 MB
  bfu*   Mb    = (bfu*)(w + 75497472);    // [8][512][512] 4 MB (dead after sme)
  float* invD2 = (float*)(w + 75497472);  // [8][8192] 256 KB, overlays dead Mb
  bfu*   Ncat  = (bfu*)(w + 79691776);    // [512][4096]   4 MB
  float* cb    = (float*)(w + 83886080);  // [8][512]     16 KB
  // ddp scratch lives in d_out (dead until gemm_fin; inv_k runs between):
  float* ddp   = out;                     // [8192][8][4]  1 MB

  // all bf16 input conversions in one pass
  conv_all<<<dim3(10240), 256, 0, stream>>>(enc0, enc1, Wc, encb, Wcb);

  dim3 tb(32, 8, 1);
  convT_x<<<dim3(16, 256, 1), tb, 0, stream>>>(X, Xb, XTb, 8192, 512);

  // [K;V] = [enc0;enc1] @ X: stacked gemm (M=1024), split-K=8, PIPE=3 counted
  gemm_kv<<<dim3(4, 16, 8), 256, 0, stream>>>(encb, XTb, KVp32);
  reduce_kv2<<<dim3(2048), 256, 0, stream>>>(KVp32, K32, V32, Kb);
  // merged transposes: Wq (z<8) + V (z=8)
  transpose_wqv<<<dim3(16, 16, 9), tb, 0, stream>>>(Wq, WqTb, V32, VTb);
  cvec_k<<<dim3(1024), 256, 0, stream>>>(K32, bq, cb);

  // merged M/N gemms, PIPE=3 counted (z<8: M_h; z>=8: N_h)
  gemm_mn<<<dim3(4, 8, 16), 256, 0, stream>>>(Kb, WqTb, Mb, Wcb, VTb, Ncat);

  // fused logits+exp -> Ecat (unnormalized) + row-sum partials -> ddp
  gemm_sme<<<dim3(2048), 256, 0, stream>>>(Xb, Mb, Ecat, cb, ddp);
  inv_k<<<dim3(256), 256, 0, stream>>>(ddp, invD2);

  // out = bc + sum_h (Ecat_h @ Ncat_h^T) / D_h
  gemm_fin<<<dim3(512), 256, 0, stream>>>(Ecat, Ncat, out, bc, invD2);
}